// Round 2
// baseline (494.888 us; speedup 1.0000x reference)
//
#include <hip/hip_runtime.h>
#include <hip/hip_bf16.h>

typedef __attribute__((ext_vector_type(8))) short short8;
typedef __attribute__((ext_vector_type(4))) float f32x4;

__device__ __forceinline__ unsigned short f32_bf16(float f) {
  union { float f; unsigned int u; } v; v.f = f;
  unsigned int r = v.u + 0x7fffu + ((v.u >> 16) & 1u);  // round-to-nearest-even
  return (unsigned short)(r >> 16);
}

__device__ __forceinline__ void load_lds16(const void* g, void* l) {
  __builtin_amdgcn_global_load_lds((const __attribute__((address_space(1))) unsigned int*)g,
                                   (__attribute__((address_space(3))) unsigned int*)l,
                                   16, 0, 0);
}

// ---------------- weight conversion: f32 -> bf16, Wp zero-padded to 96 rows ----
#define N_W1 12845056   // 1024*12544
#define N_W2 1048576    // 1024*1024
#define N_WP_REAL 95232 // 93*1024
#define N_WP_PAD 98304  // 96*1024
#define CVT_TOTAL (N_W1 + N_W2 + N_WP_PAD)

__global__ __launch_bounds__(256) void cvt_weights(
    const float* __restrict__ W1, const float* __restrict__ W2,
    const float* __restrict__ Wp, unsigned short* __restrict__ out) {
  size_t i4 = ((size_t)blockIdx.x * 256 + threadIdx.x) * 4;
  if (i4 >= (size_t)CVT_TOTAL) return;
  float a, b, c, d;
  if (i4 < N_W1) {
    const float4 v = *(const float4*)(W1 + i4); a = v.x; b = v.y; c = v.z; d = v.w;
  } else if (i4 < N_W1 + N_W2) {
    const float4 v = *(const float4*)(W2 + (i4 - N_W1)); a = v.x; b = v.y; c = v.z; d = v.w;
  } else {
    size_t l = i4 - N_W1 - N_W2;
    if (l < N_WP_REAL) { const float4 v = *(const float4*)(Wp + l); a = v.x; b = v.y; c = v.z; d = v.w; }
    else { a = b = c = d = 0.0f; }
  }
  unsigned long long pk = (unsigned long long)f32_bf16(a)
                        | ((unsigned long long)f32_bf16(b) << 16)
                        | ((unsigned long long)f32_bf16(c) << 32)
                        | ((unsigned long long)f32_bf16(d) << 48);
  *(unsigned long long*)(out + i4) = pk;
}

// ---------------- ROI align: one block per box -> X bf16 [2048][12544] --------
__global__ __launch_bounds__(256) void roi_pool_kernel(
    const float* __restrict__ p3, const float* __restrict__ p4, const float* __restrict__ p5,
    const float* __restrict__ bbox, const int* __restrict__ anchor,
    unsigned short* __restrict__ X) {
  const int m = blockIdx.x;
  const int b = m >> 9;  // N=512
  const int lvl = anchor[m] / 3;
  const float* feat; int S; float scale;
  if (lvl == 0)      { feat = p3; S = 128; scale = 0.125f;   }
  else if (lvl == 1) { feat = p4; S = 64;  scale = 0.0625f;  }
  else               { feat = p5; S = 32;  scale = 0.03125f; }
  const float* fb = feat + (size_t)b * 256 * S * S;
  const float* bx = bbox + (size_t)m * 4;
  const float x1 = bx[0] * scale - 0.5f;
  const float y1 = bx[1] * scale - 0.5f;
  const float x2 = bx[2] * scale - 0.5f;
  const float y2 = bx[3] * scale - 0.5f;
  const float bw = (x2 - x1) * (1.0f / 7.0f);
  const float bh = (y2 - y1) * (1.0f / 7.0f);
  const float fS = (float)S;
  unsigned short* xrow = X + (size_t)m * 12544;

  for (int o = threadIdx.x; o < 12544; o += 256) {
    const int c = o / 49;
    const int p = o - c * 49;
    const int py = p / 7;
    const int px = p - py * 7;
    const float* fc = fb + (size_t)c * S * S;
    float sum = 0.0f;
#pragma unroll
    for (int sy = 0; sy < 2; ++sy) {
      const float y = y1 + bh * ((float)py + (sy ? 0.75f : 0.25f));
      const float my = (y >= -1.0f && y <= fS) ? 1.0f : 0.0f;
      const float cy = fminf(fmaxf(y, 0.0f), fS - 1.0f);
      const int y0 = (int)cy;                       // floor (cy >= 0)
      const float ly = cy - (float)y0;
      const float hy = 1.0f - ly;
      const int y1i = (y0 + 1 < S) ? y0 + 1 : S - 1;
      const float* r0 = fc + (size_t)y0 * S;
      const float* r1 = fc + (size_t)y1i * S;
#pragma unroll
      for (int sx = 0; sx < 2; ++sx) {
        const float x = x1 + bw * ((float)px + (sx ? 0.75f : 0.25f));
        const float mx = (x >= -1.0f && x <= fS) ? 1.0f : 0.0f;
        const float cx = fminf(fmaxf(x, 0.0f), fS - 1.0f);
        const int x0 = (int)cx;
        const float lx = cx - (float)x0;
        const float hx = 1.0f - lx;
        const int x1i = (x0 + 1 < S) ? x0 + 1 : S - 1;
        const float v = hy * (hx * r0[x0] + lx * r0[x1i])
                      + ly * (hx * r1[x0] + lx * r1[x1i]);
        sum += v * (my * mx);
      }
    }
    xrow[o] = f32_bf16(sum * 0.25f);
  }
}

// ---------------- split-K BT-GEMM: Cpart[s] = A[M][K]·B[N][K]^T (bf16, f32 acc)
template<int BM, int BN, int WGM, int WGN>
__global__ __launch_bounds__(256)
void gemm_bt_splitk(const unsigned short* __restrict__ A, int lda,
                    const unsigned short* __restrict__ B, int ldb,
                    float* __restrict__ Cpart, int M, int N, int Ksplit) {
  constexpr int BK = 64;
  constexpr int WM = BM / WGM, WN = BN / WGN;
  constexpr int FM = WM / 16, FN = WN / 16;
  constexpr int AITER = BM * BK / 2048;   // 256 lanes * 8 elems per iter
  constexpr int BITER = BN * BK / 2048;
  __shared__ unsigned short Asm_[BM * BK];
  __shared__ unsigned short Bsm_[BN * BK];
  const int tid = threadIdx.x;
  const int wave = tid >> 6, lane = tid & 63;
  const int wr = wave / WGN, wc = wave % WGN;
  const int m0 = blockIdx.x * BM, n0 = blockIdx.y * BN;
  const int kbase0 = blockIdx.z * Ksplit;

  f32x4 acc[FM][FN];
#pragma unroll
  for (int i = 0; i < FM; ++i)
#pragma unroll
    for (int j = 0; j < FN; ++j)
      acc[i][j] = f32x4{0.0f, 0.0f, 0.0f, 0.0f};

  const int ar = tid >> 3;            // staging row within 32-row group
  const int acsub = (tid & 7) * 8;    // staging col (elements)
  const int fr = lane & 15;
  const int kq = (lane >> 4) * 8;

  for (int kt = 0; kt < Ksplit; kt += BK) {
    const int kb = kbase0 + kt;
#pragma unroll
    for (int it = 0; it < AITER; ++it) {
      const unsigned short* src = A + (size_t)(m0 + it * 32 + ar) * lda + kb + acsub;
      load_lds16(src, (char*)Asm_ + it * 4096 + wave * 1024);
    }
#pragma unroll
    for (int it = 0; it < BITER; ++it) {
      const unsigned short* src = B + (size_t)(n0 + it * 32 + ar) * ldb + kb + acsub;
      load_lds16(src, (char*)Bsm_ + it * 4096 + wave * 1024);
    }
    __syncthreads();   // compiler inserts vmcnt(0) drain before barrier
#pragma unroll
    for (int kk = 0; kk < BK; kk += 32) {
      short8 af[FM], bfr[FN];
#pragma unroll
      for (int i = 0; i < FM; ++i)
        af[i] = *(const short8*)(Asm_ + (wr * WM + i * 16 + fr) * BK + kk + kq);
#pragma unroll
      for (int j = 0; j < FN; ++j)
        bfr[j] = *(const short8*)(Bsm_ + (wc * WN + j * 16 + fr) * BK + kk + kq);
#pragma unroll
      for (int i = 0; i < FM; ++i)
#pragma unroll
        for (int j = 0; j < FN; ++j)
          acc[i][j] = __builtin_amdgcn_mfma_f32_16x16x32_bf16(af[i], bfr[j], acc[i][j], 0, 0, 0);
    }
    __syncthreads();
  }

  float* Cp = Cpart + (size_t)blockIdx.z * ((size_t)M * N);
  const int rq = (lane >> 4) * 4;
  const int cq = lane & 15;
#pragma unroll
  for (int i = 0; i < FM; ++i)
#pragma unroll
    for (int j = 0; j < FN; ++j) {
      const int row = m0 + wr * WM + i * 16 + rq;
      const int col = n0 + wc * WN + j * 16 + cq;
      float* o = Cp + (size_t)row * N + col;
#pragma unroll
      for (int q = 0; q < 4; ++q)
        o[(size_t)q * N] = acc[i][j][q];
    }
}

// ---------------- split-K reduction + bias (+ReLU) -> bf16 --------------------
template<int S, bool RELU>
__global__ __launch_bounds__(256) void reduce_bias_bf16(
    const float* __restrict__ P, const float* __restrict__ bias,
    unsigned short* __restrict__ out, int MN, int Nmask) {
  const int i = blockIdx.x * 256 + threadIdx.x;
  if (i >= MN) return;
  float s = bias[i & Nmask];
#pragma unroll
  for (int j = 0; j < S; ++j) s += P[(size_t)j * MN + i];
  if (RELU) s = fmaxf(s, 0.0f);
  out[i] = f32_bf16(s);
}

__global__ __launch_bounds__(256) void reduce_out(
    const float* __restrict__ P, const float* __restrict__ bp,
    float* __restrict__ out) {
  const int i = blockIdx.x * 256 + threadIdx.x;
  if (i >= 2048 * 93) return;
  const int mrow = i / 93;
  const int n = i - mrow * 93;
  float s = bp[n];
#pragma unroll
  for (int j = 0; j < 8; ++j) s += P[(size_t)j * (2048 * 96) + mrow * 96 + n];
  out[i] = s;
}

// ---------------- launch ------------------------------------------------------
extern "C" void kernel_launch(void* const* d_in, const int* in_sizes, int n_in,
                              void* d_out, int out_size, void* d_ws, size_t ws_size,
                              hipStream_t stream) {
  const float* p3   = (const float*)d_in[0];
  const float* p4   = (const float*)d_in[1];
  const float* p5   = (const float*)d_in[2];
  const float* bbox = (const float*)d_in[3];
  const int*   anc  = (const int*)d_in[4];
  const float* W1   = (const float*)d_in[5];
  const float* b1   = (const float*)d_in[6];
  const float* W2   = (const float*)d_in[7];
  const float* b2   = (const float*)d_in[8];
  const float* Wp   = (const float*)d_in[9];
  const float* bp   = (const float*)d_in[10];
  float* out = (float*)d_out;

  char* ws = (char*)d_ws;
  // ws layout (bytes, all 256-aligned):
  unsigned short* W1b = (unsigned short*)(ws);              // 25,690,112
  unsigned short* W2b = (unsigned short*)(ws + 25690112);   //  2,097,152
  unsigned short* Wpb = (unsigned short*)(ws + 27787264);   //    196,608 (padded 96 rows)
  unsigned short* X   = (unsigned short*)(ws + 27983872);   // 51,380,224
  unsigned short* H1  = (unsigned short*)(ws + 79364096);   //  4,194,304
  unsigned short* H2  = (unsigned short*)(ws + 83558400);   //  4,194,304
  float*          P   = (float*)(ws + 87752704);            // 33,554,432 (reused by all 3 GEMMs)
  (void)ws_size; (void)in_sizes; (void)n_in; (void)out_size;

  // 1. weights -> bf16 (W1b | W2b | Wpb contiguous)
  hipLaunchKernelGGL(cvt_weights, dim3(13664), dim3(256), 0, stream, W1, W2, Wp, W1b);
  // 2. ROI align -> X bf16 [2048][12544]
  hipLaunchKernelGGL(roi_pool_kernel, dim3(2048), dim3(256), 0, stream, p3, p4, p5, bbox, anc, X);
  // 3. FC1: X @ W1^T, split-K=4
  hipLaunchKernelGGL((gemm_bt_splitk<128,128,2,2>), dim3(16, 8, 4), dim3(256), 0, stream,
                     X, 12544, W1b, 12544, P, 2048, 1024, 3136);
  hipLaunchKernelGGL((reduce_bias_bf16<4,true>), dim3(8192), dim3(256), 0, stream,
                     P, b1, H1, 2048 * 1024, 1023);
  // 4. FC2: H1 @ W2^T, split-K=2
  hipLaunchKernelGGL((gemm_bt_splitk<128,128,2,2>), dim3(16, 8, 2), dim3(256), 0, stream,
                     H1, 1024, W2b, 1024, P, 2048, 1024, 512);
  hipLaunchKernelGGL((reduce_bias_bf16<2,true>), dim3(8192), dim3(256), 0, stream,
                     P, b2, H2, 2048 * 1024, 1023);
  // 5. proj: H2 @ Wp^T (N padded to 96), split-K=8
  hipLaunchKernelGGL((gemm_bt_splitk<128,96,4,1>), dim3(16, 1, 8), dim3(256), 0, stream,
                     H2, 1024, Wpb, 1024, P, 2048, 96, 128);
  hipLaunchKernelGGL(reduce_out, dim3(744), dim3(256), 0, stream, P, bp, out);
}

// Round 5
// 214.996 us; speedup vs baseline: 2.3018x; 2.3018x over previous
//
#include <hip/hip_runtime.h>
#include <hip/hip_bf16.h>

typedef unsigned short u16;
typedef __attribute__((ext_vector_type(8))) short short8;
typedef __attribute__((ext_vector_type(4))) float f32x4;
typedef __attribute__((ext_vector_type(4))) unsigned short us4;

__device__ __forceinline__ u16 f32_bf16(float f) {
  union { float f; unsigned int u; } v; v.f = f;
  unsigned int r = v.u + 0x7fffu + ((v.u >> 16) & 1u);  // round-to-nearest-even
  return (u16)(r >> 16);
}
__device__ __forceinline__ float bf16_f32(u16 h) {
  union { unsigned int u; float f; } v; v.u = ((unsigned int)h) << 16; return v.f;
}

__device__ __forceinline__ void load_lds16(const void* g, void* l) {
  __builtin_amdgcn_global_load_lds((const __attribute__((address_space(1))) unsigned int*)g,
                                   (__attribute__((address_space(3))) unsigned int*)l,
                                   16, 0, 0);
}

// ---------------- generic f32 -> bf16 (vectorized ×4) -------------------------
__global__ __launch_bounds__(256) void cvt_f32_bf16(
    const float* __restrict__ src, u16* __restrict__ dst, int n4) {
  int i = blockIdx.x * 256 + threadIdx.x;
  if (i >= n4) return;
  const float4 v = ((const float4*)src)[i];
  unsigned long long pk = (unsigned long long)f32_bf16(v.x)
                        | ((unsigned long long)f32_bf16(v.y) << 16)
                        | ((unsigned long long)f32_bf16(v.z) << 32)
                        | ((unsigned long long)f32_bf16(v.w) << 48);
  ((unsigned long long*)dst)[i] = pk;
}

// Wp: 93x1024 f32 -> 96x1024 bf16 zero-padded
__global__ __launch_bounds__(256) void cvt_wp(
    const float* __restrict__ src, u16* __restrict__ dst) {
  int i = blockIdx.x * 256 + threadIdx.x;   // quads; 24576 total
  if (i >= 24576) return;
  int e = i * 4;
  float4 v = (e < 95232) ? ((const float4*)src)[i] : float4{0.f, 0.f, 0.f, 0.f};
  unsigned long long pk = (unsigned long long)f32_bf16(v.x)
                        | ((unsigned long long)f32_bf16(v.y) << 16)
                        | ((unsigned long long)f32_bf16(v.z) << 32)
                        | ((unsigned long long)f32_bf16(v.w) << 48);
  ((unsigned long long*)dst)[i] = pk;
}

// ---------------- feature transpose: [B,C,S,S] f32 -> [B,S,S,C] bf16 ----------
// Tile: 64 channels x 16 x-positions. Blocks: p3 16384 | p4 4096 | p5 1024.
__global__ __launch_bounds__(256) void transpose_feats(
    const float* __restrict__ p3, const float* __restrict__ p4, const float* __restrict__ p5,
    u16* __restrict__ t3, u16* __restrict__ t4, u16* __restrict__ t5) {
  const int bid = blockIdx.x;
  const float* src; u16* dst; int S, tile;
  if (bid < 16384)      { src = p3; dst = t3; S = 128; tile = bid; }
  else if (bid < 20480) { src = p4; dst = t4; S = 64;  tile = bid - 16384; }
  else                  { src = p5; dst = t5; S = 32;  tile = bid - 20480; }
  const int cchunk = tile & 3;
  const int fp0 = (tile >> 2) * 16;        // flat position b*S*S + pimg (16-aligned, one row)
  const int SS = S * S;
  const int b = fp0 / SS;
  const int pimg = fp0 - b * SS;
  __shared__ __align__(16) u16 lds[16 * 72];
  const int t = threadIdx.x;
  {
    const int cl = t >> 2, xv = t & 3;
    const int c = cchunk * 64 + cl;
    const float4 v = *(const float4*)(src + (size_t)(b * 256 + c) * SS + pimg + xv * 4);
    lds[(xv * 4 + 0) * 72 + cl] = f32_bf16(v.x);
    lds[(xv * 4 + 1) * 72 + cl] = f32_bf16(v.y);
    lds[(xv * 4 + 2) * 72 + cl] = f32_bf16(v.z);
    lds[(xv * 4 + 3) * 72 + cl] = f32_bf16(v.w);
  }
  __syncthreads();
  {
    const int xl = t >> 4, cg = (t & 15) * 4;
    const us4 h = *(const us4*)&lds[xl * 72 + cg];
    *(us4*)(dst + (size_t)(fp0 + xl) * 256 + cchunk * 64 + cg) = h;
  }
}

// ---------------- ROI align v2: channels-last gather -> X bf16 [2048][12544] --
__global__ __launch_bounds__(256) void roi_pool2(
    const u16* __restrict__ t3, const u16* __restrict__ t4, const u16* __restrict__ t5,
    const float* __restrict__ bbox, const int* __restrict__ anchor,
    u16* __restrict__ X) {
  const int m = blockIdx.x;
  const int b = m >> 9;  // N=512
  const int lvl = anchor[m] / 3;
  const u16* ft; int S; float scale;
  if (lvl == 0)      { ft = t3; S = 128; scale = 0.125f;   }
  else if (lvl == 1) { ft = t4; S = 64;  scale = 0.0625f;  }
  else               { ft = t5; S = 32;  scale = 0.03125f; }
  ft += (size_t)b * S * S * 256;
  const float* bx = bbox + (size_t)m * 4;
  const float x1 = bx[0] * scale - 0.5f;
  const float y1 = bx[1] * scale - 0.5f;
  const float bw = (bx[2] * scale - 0.5f - x1) * (1.0f / 7.0f);
  const float bh = (bx[3] * scale - 0.5f - y1) * (1.0f / 7.0f);
  const float fS = (float)S;

  __shared__ __align__(16) u16 xs[12544];
  const int wave = threadIdx.x >> 6, lane = threadIdx.x & 63;
  const int cbase = lane * 4;

  for (int p = wave; p < 49; p += 4) {
    const int py = p / 7, px = p - py * 7;
    float s0 = 0.f, s1 = 0.f, s2 = 0.f, s3 = 0.f;
#pragma unroll
    for (int sy = 0; sy < 2; ++sy) {
      const float y = y1 + bh * ((float)py + (sy ? 0.75f : 0.25f));
      const float my = (y >= -1.0f && y <= fS) ? 1.0f : 0.0f;
      const float cy = fminf(fmaxf(y, 0.0f), fS - 1.0f);
      const int y0 = (int)cy;
      const float ly = cy - (float)y0;
      const float hy = 1.0f - ly;
      const int y1i = (y0 + 1 < S) ? y0 + 1 : S - 1;
#pragma unroll
      for (int sx = 0; sx < 2; ++sx) {
        const float x = x1 + bw * ((float)px + (sx ? 0.75f : 0.25f));
        const float mx = (x >= -1.0f && x <= fS) ? 1.0f : 0.0f;
        const float cx = fminf(fmaxf(x, 0.0f), fS - 1.0f);
        const int x0 = (int)cx;
        const float lx = cx - (float)x0;
        const float hx = 1.0f - lx;
        const int x1i = (x0 + 1 < S) ? x0 + 1 : S - 1;
        const us4 f00 = *(const us4*)(ft + (size_t)(y0  * S + x0 ) * 256 + cbase);
        const us4 f01 = *(const us4*)(ft + (size_t)(y0  * S + x1i) * 256 + cbase);
        const us4 f10 = *(const us4*)(ft + (size_t)(y1i * S + x0 ) * 256 + cbase);
        const us4 f11 = *(const us4*)(ft + (size_t)(y1i * S + x1i) * 256 + cbase);
        const float msk = my * mx;
        const float w00 = hy * hx * msk, w01 = hy * lx * msk;
        const float w10 = ly * hx * msk, w11 = ly * lx * msk;
        s0 += w00 * bf16_f32(f00.x) + w01 * bf16_f32(f01.x) + w10 * bf16_f32(f10.x) + w11 * bf16_f32(f11.x);
        s1 += w00 * bf16_f32(f00.y) + w01 * bf16_f32(f01.y) + w10 * bf16_f32(f10.y) + w11 * bf16_f32(f11.y);
        s2 += w00 * bf16_f32(f00.z) + w01 * bf16_f32(f01.z) + w10 * bf16_f32(f10.z) + w11 * bf16_f32(f11.z);
        s3 += w00 * bf16_f32(f00.w) + w01 * bf16_f32(f01.w) + w10 * bf16_f32(f10.w) + w11 * bf16_f32(f11.w);
      }
    }
    xs[(cbase + 0) * 49 + p] = f32_bf16(s0 * 0.25f);
    xs[(cbase + 1) * 49 + p] = f32_bf16(s1 * 0.25f);
    xs[(cbase + 2) * 49 + p] = f32_bf16(s2 * 0.25f);
    xs[(cbase + 3) * 49 + p] = f32_bf16(s3 * 0.25f);
  }
  __syncthreads();
  uint4* dst = (uint4*)(X + (size_t)m * 12544);
  const uint4* srcl = (const uint4*)xs;
  for (int i = threadIdx.x; i < 1568; i += 256) dst[i] = srcl[i];
}

// ---------------- split-K BT-GEMM: Cpart[s] = A[M][K]·B[N][K]^T (bf16, f32 acc)
template<int BM, int BN, int WGM, int WGN>
__global__ __launch_bounds__(256)
void gemm_bt_splitk(const u16* __restrict__ A, int lda,
                    const u16* __restrict__ B, int ldb,
                    float* __restrict__ Cpart, int M, int N, int Ksplit) {
  constexpr int BK = 64;
  constexpr int WM = BM / WGM, WN = BN / WGN;
  constexpr int FM = WM / 16, FN = WN / 16;
  constexpr int AITER = BM * BK / 2048;
  constexpr int BITER = BN * BK / 2048;
  __shared__ u16 Asm_[BM * BK];
  __shared__ u16 Bsm_[BN * BK];
  const int tid = threadIdx.x;
  const int wave = tid >> 6, lane = tid & 63;
  const int wr = wave / WGN, wc = wave % WGN;
  const int m0 = blockIdx.x * BM, n0 = blockIdx.y * BN;
  const int kbase0 = blockIdx.z * Ksplit;

  f32x4 acc[FM][FN];
#pragma unroll
  for (int i = 0; i < FM; ++i)
#pragma unroll
    for (int j = 0; j < FN; ++j)
      acc[i][j] = f32x4{0.0f, 0.0f, 0.0f, 0.0f};

  const int ar = tid >> 3;
  const int acsub = (tid & 7) * 8;
  const int fr = lane & 15;
  const int kq = (lane >> 4) * 8;

  for (int kt = 0; kt < Ksplit; kt += BK) {
    const int kb = kbase0 + kt;
#pragma unroll
    for (int it = 0; it < AITER; ++it) {
      const u16* src = A + (size_t)(m0 + it * 32 + ar) * lda + kb + acsub;
      load_lds16(src, (char*)Asm_ + it * 4096 + wave * 1024);
    }
#pragma unroll
    for (int it = 0; it < BITER; ++it) {
      const u16* src = B + (size_t)(n0 + it * 32 + ar) * ldb + kb + acsub;
      load_lds16(src, (char*)Bsm_ + it * 4096 + wave * 1024);
    }
    __syncthreads();
#pragma unroll
    for (int kk = 0; kk < BK; kk += 32) {
      short8 af[FM], bfr[FN];
#pragma unroll
      for (int i = 0; i < FM; ++i)
        af[i] = *(const short8*)(Asm_ + (wr * WM + i * 16 + fr) * BK + kk + kq);
#pragma unroll
      for (int j = 0; j < FN; ++j)
        bfr[j] = *(const short8*)(Bsm_ + (wc * WN + j * 16 + fr) * BK + kk + kq);
#pragma unroll
      for (int i = 0; i < FM; ++i)
#pragma unroll
        for (int j = 0; j < FN; ++j)
          acc[i][j] = __builtin_amdgcn_mfma_f32_16x16x32_bf16(af[i], bfr[j], acc[i][j], 0, 0, 0);
    }
    __syncthreads();
  }

  float* Cp = Cpart + (size_t)blockIdx.z * ((size_t)M * N);
  const int rq = (lane >> 4) * 4;
  const int cq = lane & 15;
#pragma unroll
  for (int i = 0; i < FM; ++i)
#pragma unroll
    for (int j = 0; j < FN; ++j) {
      const int row = m0 + wr * WM + i * 16 + rq;
      const int col = n0 + wc * WN + j * 16 + cq;
      float* o = Cp + (size_t)row * N + col;
#pragma unroll
      for (int q = 0; q < 4; ++q)
        o[(size_t)q * N] = acc[i][j][q];
    }
}

// ---------------- split-K reduction + bias (+ReLU) -> bf16 --------------------
template<int S, bool RELU>
__global__ __launch_bounds__(256) void reduce_bias_bf16(
    const float* __restrict__ P, const float* __restrict__ bias,
    u16* __restrict__ out, int MN, int Nmask) {
  const int i = blockIdx.x * 256 + threadIdx.x;
  if (i >= MN) return;
  float s = bias[i & Nmask];
#pragma unroll
  for (int j = 0; j < S; ++j) s += P[(size_t)j * MN + i];
  if (RELU) s = fmaxf(s, 0.0f);
  out[i] = f32_bf16(s);
}

__global__ __launch_bounds__(256) void reduce_out(
    const float* __restrict__ P, const float* __restrict__ bp,
    float* __restrict__ out) {
  const int i = blockIdx.x * 256 + threadIdx.x;
  if (i >= 2048 * 93) return;
  const int mrow = i / 93;
  const int n = i - mrow * 93;
  float s = bp[n];
#pragma unroll
  for (int j = 0; j < 8; ++j) s += P[(size_t)j * (2048 * 96) + mrow * 96 + n];
  out[i] = s;
}

// ---------------- launch ------------------------------------------------------
extern "C" void kernel_launch(void* const* d_in, const int* in_sizes, int n_in,
                              void* d_out, int out_size, void* d_ws, size_t ws_size,
                              hipStream_t stream) {
  const float* p3   = (const float*)d_in[0];
  const float* p4   = (const float*)d_in[1];
  const float* p5   = (const float*)d_in[2];
  const float* bbox = (const float*)d_in[3];
  const int*   anc  = (const int*)d_in[4];
  const float* W1   = (const float*)d_in[5];
  const float* b1   = (const float*)d_in[6];
  const float* W2   = (const float*)d_in[7];
  const float* b2   = (const float*)d_in[8];
  const float* Wp   = (const float*)d_in[9];
  const float* bp   = (const float*)d_in[10];
  float* out = (float*)d_out;

  char* ws = (char*)d_ws;
  // Permanent: X [0, 51380224), W1b [51380224, 77070336)
  u16* X   = (u16*)(ws);
  u16* W1b = (u16*)(ws + 51380224);
  // Shared region R at 77070336 (size 44236800; total 121307136 == round-0 usage):
  //   Phase A (transpose+roi): ft_t = t3|t4|t5 (44040192 B)
  //   Phase B (after roi):     W2b|Wpb|H1|H2|P (44236800 B)
  char* R = ws + 77070336;
  u16* t3  = (u16*)(R);
  u16* t4  = (u16*)(R + 33554432);
  u16* t5  = (u16*)(R + 41943040);
  u16* W2b = (u16*)(R);
  u16* Wpb = (u16*)(R + 2097152);
  u16* H1  = (u16*)(R + 2293760);
  u16* H2  = (u16*)(R + 6488064);
  float* P = (float*)(R + 10682368);
  (void)ws_size; (void)in_sizes; (void)n_in; (void)out_size;

  // Phase A: transpose feats to channels-last bf16, then ROI gather
  hipLaunchKernelGGL(transpose_feats, dim3(21504), dim3(256), 0, stream, p3, p4, p5, t3, t4, t5);
  hipLaunchKernelGGL(roi_pool2, dim3(2048), dim3(256), 0, stream, t3, t4, t5, bbox, anc, X);
  // Phase B: weights -> bf16 (W2b/Wpb overwrite ft_t region -> must follow roi)
  hipLaunchKernelGGL(cvt_f32_bf16, dim3(12544), dim3(256), 0, stream, W1, W1b, 3211264);
  hipLaunchKernelGGL(cvt_f32_bf16, dim3(1024), dim3(256), 0, stream, W2, W2b, 262144);
  hipLaunchKernelGGL(cvt_wp, dim3(96), dim3(256), 0, stream, Wp, Wpb);
  // FC1: X @ W1^T, split-K=4
  hipLaunchKernelGGL((gemm_bt_splitk<128,128,2,2>), dim3(16, 8, 4), dim3(256), 0, stream,
                     X, 12544, W1b, 12544, P, 2048, 1024, 3136);
  hipLaunchKernelGGL((reduce_bias_bf16<4,true>), dim3(8192), dim3(256), 0, stream,
                     P, b1, H1, 2048 * 1024, 1023);
  // FC2: H1 @ W2^T, split-K=2
  hipLaunchKernelGGL((gemm_bt_splitk<128,128,2,2>), dim3(16, 8, 2), dim3(256), 0, stream,
                     H1, 1024, W2b, 1024, P, 2048, 1024, 512);
  hipLaunchKernelGGL((reduce_bias_bf16<2,true>), dim3(8192), dim3(256), 0, stream,
                     P, b2, H2, 2048 * 1024, 1023);
  // proj: H2 @ Wp^T (N padded to 96), split-K=8
  hipLaunchKernelGGL((gemm_bt_splitk<128,96,4,1>), dim3(16, 1, 8), dim3(256), 0, stream,
                     H2, 1024, Wpb, 1024, P, 2048, 96, 128);
  hipLaunchKernelGGL(reduce_out, dim3(744), dim3(256), 0, stream, P, bp, out);
}

// Round 6
// 193.066 us; speedup vs baseline: 2.5633x; 1.1136x over previous
//
#include <hip/hip_runtime.h>
#include <hip/hip_bf16.h>

typedef unsigned short u16;
typedef __attribute__((ext_vector_type(8))) short short8;
typedef __attribute__((ext_vector_type(4))) float f32x4;
typedef __attribute__((ext_vector_type(4))) unsigned short us4;

__device__ __forceinline__ u16 f32_bf16(float f) {
  union { float f; unsigned int u; } v; v.f = f;
  unsigned int r = v.u + 0x7fffu + ((v.u >> 16) & 1u);  // round-to-nearest-even
  return (u16)(r >> 16);
}
__device__ __forceinline__ float bf16_f32(u16 h) {
  union { unsigned int u; float f; } v; v.u = ((unsigned int)h) << 16; return v.f;
}

__device__ __forceinline__ void load_lds16(const void* g, void* l) {
  __builtin_amdgcn_global_load_lds((const __attribute__((address_space(1))) unsigned int*)g,
                                   (__attribute__((address_space(3))) unsigned int*)l,
                                   16, 0, 0);
}

// ---------------- generic f32 -> bf16 (vectorized ×4) -------------------------
__global__ __launch_bounds__(256) void cvt_f32_bf16(
    const float* __restrict__ src, u16* __restrict__ dst, int n4) {
  int i = blockIdx.x * 256 + threadIdx.x;
  if (i >= n4) return;
  const float4 v = ((const float4*)src)[i];
  unsigned long long pk = (unsigned long long)f32_bf16(v.x)
                        | ((unsigned long long)f32_bf16(v.y) << 16)
                        | ((unsigned long long)f32_bf16(v.z) << 32)
                        | ((unsigned long long)f32_bf16(v.w) << 48);
  ((unsigned long long*)dst)[i] = pk;
}

// Wp: 93x1024 f32 -> 96x1024 bf16 zero-padded
__global__ __launch_bounds__(256) void cvt_wp(
    const float* __restrict__ src, u16* __restrict__ dst) {
  int i = blockIdx.x * 256 + threadIdx.x;   // quads; 24576 total
  if (i >= 24576) return;
  int e = i * 4;
  float4 v = (e < 95232) ? ((const float4*)src)[i] : float4{0.f, 0.f, 0.f, 0.f};
  unsigned long long pk = (unsigned long long)f32_bf16(v.x)
                        | ((unsigned long long)f32_bf16(v.y) << 16)
                        | ((unsigned long long)f32_bf16(v.z) << 32)
                        | ((unsigned long long)f32_bf16(v.w) << 48);
  ((unsigned long long*)dst)[i] = pk;
}

// ---------------- feature transpose: [B,C,S,S] f32 -> [B,S,S,C] bf16 ----------
__global__ __launch_bounds__(256) void transpose_feats(
    const float* __restrict__ p3, const float* __restrict__ p4, const float* __restrict__ p5,
    u16* __restrict__ t3, u16* __restrict__ t4, u16* __restrict__ t5) {
  const int bid = blockIdx.x;
  const float* src; u16* dst; int S, tile;
  if (bid < 16384)      { src = p3; dst = t3; S = 128; tile = bid; }
  else if (bid < 20480) { src = p4; dst = t4; S = 64;  tile = bid - 16384; }
  else                  { src = p5; dst = t5; S = 32;  tile = bid - 20480; }
  const int cchunk = tile & 3;
  const int fp0 = (tile >> 2) * 16;
  const int SS = S * S;
  const int b = fp0 / SS;
  const int pimg = fp0 - b * SS;
  __shared__ __align__(16) u16 lds[16 * 72];
  const int t = threadIdx.x;
  {
    const int cl = t >> 2, xv = t & 3;
    const int c = cchunk * 64 + cl;
    const float4 v = *(const float4*)(src + (size_t)(b * 256 + c) * SS + pimg + xv * 4);
    lds[(xv * 4 + 0) * 72 + cl] = f32_bf16(v.x);
    lds[(xv * 4 + 1) * 72 + cl] = f32_bf16(v.y);
    lds[(xv * 4 + 2) * 72 + cl] = f32_bf16(v.z);
    lds[(xv * 4 + 3) * 72 + cl] = f32_bf16(v.w);
  }
  __syncthreads();
  {
    const int xl = t >> 4, cg = (t & 15) * 4;
    const us4 h = *(const us4*)&lds[xl * 72 + cg];
    *(us4*)(dst + (size_t)(fp0 + xl) * 256 + cchunk * 64 + cg) = h;
  }
}

// ---------------- ROI align: channels-last gather -> X bf16 [2048][12544] -----
__global__ __launch_bounds__(256) void roi_pool2(
    const u16* __restrict__ t3, const u16* __restrict__ t4, const u16* __restrict__ t5,
    const float* __restrict__ bbox, const int* __restrict__ anchor,
    u16* __restrict__ X) {
  const int m = blockIdx.x;
  const int b = m >> 9;
  const int lvl = anchor[m] / 3;
  const u16* ft; int S; float scale;
  if (lvl == 0)      { ft = t3; S = 128; scale = 0.125f;   }
  else if (lvl == 1) { ft = t4; S = 64;  scale = 0.0625f;  }
  else               { ft = t5; S = 32;  scale = 0.03125f; }
  ft += (size_t)b * S * S * 256;
  const float* bx = bbox + (size_t)m * 4;
  const float x1 = bx[0] * scale - 0.5f;
  const float y1 = bx[1] * scale - 0.5f;
  const float bw = (bx[2] * scale - 0.5f - x1) * (1.0f / 7.0f);
  const float bh = (bx[3] * scale - 0.5f - y1) * (1.0f / 7.0f);
  const float fS = (float)S;

  __shared__ __align__(16) u16 xs[12544];
  const int wave = threadIdx.x >> 6, lane = threadIdx.x & 63;
  const int cbase = lane * 4;

  for (int p = wave; p < 49; p += 4) {
    const int py = p / 7, px = p - py * 7;
    float s0 = 0.f, s1 = 0.f, s2 = 0.f, s3 = 0.f;
#pragma unroll
    for (int sy = 0; sy < 2; ++sy) {
      const float y = y1 + bh * ((float)py + (sy ? 0.75f : 0.25f));
      const float my = (y >= -1.0f && y <= fS) ? 1.0f : 0.0f;
      const float cy = fminf(fmaxf(y, 0.0f), fS - 1.0f);
      const int y0 = (int)cy;
      const float ly = cy - (float)y0;
      const float hy = 1.0f - ly;
      const int y1i = (y0 + 1 < S) ? y0 + 1 : S - 1;
#pragma unroll
      for (int sx = 0; sx < 2; ++sx) {
        const float x = x1 + bw * ((float)px + (sx ? 0.75f : 0.25f));
        const float mx = (x >= -1.0f && x <= fS) ? 1.0f : 0.0f;
        const float cx = fminf(fmaxf(x, 0.0f), fS - 1.0f);
        const int x0 = (int)cx;
        const float lx = cx - (float)x0;
        const float hx = 1.0f - lx;
        const int x1i = (x0 + 1 < S) ? x0 + 1 : S - 1;
        const us4 f00 = *(const us4*)(ft + (size_t)(y0  * S + x0 ) * 256 + cbase);
        const us4 f01 = *(const us4*)(ft + (size_t)(y0  * S + x1i) * 256 + cbase);
        const us4 f10 = *(const us4*)(ft + (size_t)(y1i * S + x0 ) * 256 + cbase);
        const us4 f11 = *(const us4*)(ft + (size_t)(y1i * S + x1i) * 256 + cbase);
        const float msk = my * mx;
        const float w00 = hy * hx * msk, w01 = hy * lx * msk;
        const float w10 = ly * hx * msk, w11 = ly * lx * msk;
        s0 += w00 * bf16_f32(f00.x) + w01 * bf16_f32(f01.x) + w10 * bf16_f32(f10.x) + w11 * bf16_f32(f11.x);
        s1 += w00 * bf16_f32(f00.y) + w01 * bf16_f32(f01.y) + w10 * bf16_f32(f10.y) + w11 * bf16_f32(f11.y);
        s2 += w00 * bf16_f32(f00.z) + w01 * bf16_f32(f01.z) + w10 * bf16_f32(f10.z) + w11 * bf16_f32(f11.z);
        s3 += w00 * bf16_f32(f00.w) + w01 * bf16_f32(f01.w) + w10 * bf16_f32(f10.w) + w11 * bf16_f32(f11.w);
      }
    }
    xs[(cbase + 0) * 49 + p] = f32_bf16(s0 * 0.25f);
    xs[(cbase + 1) * 49 + p] = f32_bf16(s1 * 0.25f);
    xs[(cbase + 2) * 49 + p] = f32_bf16(s2 * 0.25f);
    xs[(cbase + 3) * 49 + p] = f32_bf16(s3 * 0.25f);
  }
  __syncthreads();
  uint4* dst = (uint4*)(X + (size_t)m * 12544);
  const uint4* srcl = (const uint4*)xs;
  for (int i = threadIdx.x; i < 1568; i += 256) dst[i] = srcl[i];
}

// ============ 256x256 phase-split pipelined BT-GEMM (bf16 partials out) =======
// 8 waves (2M x 4N), BK=64 in two K-half phases of 32. Per phase:
//   vmcnt(4) -> s_barrier -> sched_barrier -> 12 ds_read_b128 ->
//   stage K-half of tile t+1 (4 global_load_lds) -> setprio(1) 32 MFMA setprio(0)
// LDS 128 KiB: A/B x dbuf x khalf, each 16 KiB stored as 128 row-pairs x 128B,
// XOR-swizzled (byte ^= (rowpair&7)<<4) on BOTH global source and LDS read.
template<int NT>
__global__ __launch_bounds__(512, 2)
void gemm8_bt(const u16* __restrict__ A, int lda,
              const u16* __restrict__ B, int ldb,
              u16* __restrict__ Cpart, int M, int N,
              int mb, int nb) {
  __shared__ __align__(16) char lds[131072];
  const int tid = threadIdx.x;
  const int wave = tid >> 6, lane = tid & 63;
  const int wr = wave >> 2, wc = wave & 3;

  // XCD-bijective block swizzle (grid is a multiple of 8)
  const int G = gridDim.x;
  const int bid = blockIdx.x;
  const int swz = (bid & 7) * (G >> 3) + (bid >> 3);
  const int x = swz % mb;
  const int rest = swz / mb;
  const int y = rest % nb;
  const int z = rest / nb;
  const int m0 = x * 256, n0 = y * 256;
  const int kb0 = z * (NT * 64);

  // staging constants: linear LDS dest, inverse-swizzled global source
  const int sb = ((lane & 7) ^ (lane >> 3)) << 4;            // byte-in-128B-row
  const int rowb2 = 2 * (wave * 8 + (lane >> 3)) + (sb >> 6); // row within 128-row chunk
  const int keloff = (sb & 63) >> 1;                          // k-elem within half

  // fragment-read constants (swizzled ds_read addresses)
  const int frow = lane & 15;
  const int rh = frow >> 1;
  const int swb = ((((frow & 1) << 6) | ((lane >> 4) << 4))) ^ (rh << 4);
  const int a_rd = wr * 8192 + rh * 128 + swb;   // + fi*1024 + half-buf base
  const int b_rd = wc * 4096 + rh * 128 + swb;   // + fj*1024 + half-buf base

  f32x4 acc[8][4];
#pragma unroll
  for (int i = 0; i < 8; ++i)
#pragma unroll
    for (int j = 0; j < 4; ++j)
      acc[i][j] = f32x4{0.f, 0.f, 0.f, 0.f};

  auto stageAB = [&](int tile, int ph) {
    const int dst = ((tile & 1) * 2 + ph) * 16384;
    const int kel = kb0 + tile * 64 + ph * 32 + keloff;
#pragma unroll
    for (int i = 0; i < 2; ++i) {
      const u16* srcA = A + (size_t)(m0 + i * 128 + rowb2) * lda + kel;
      load_lds16(srcA, lds + dst + i * 8192 + wave * 1024);
    }
#pragma unroll
    for (int i = 0; i < 2; ++i) {
      const u16* srcB = B + (size_t)(n0 + i * 128 + rowb2) * ldb + kel;
      load_lds16(srcB, lds + 65536 + dst + i * 8192 + wave * 1024);
    }
  };

#define GPHASE(T, PH, VW, DOSTAGE)                                              \
  {                                                                             \
    asm volatile("s_waitcnt vmcnt(" VW ")" ::: "memory");                       \
    __builtin_amdgcn_s_barrier();                                               \
    __builtin_amdgcn_sched_barrier(0);                                          \
    const int hb_ = (((T) & 1) * 2 + (PH)) * 16384;                             \
    short8 af[8], bf[4];                                                        \
    _Pragma("unroll")                                                           \
    for (int fi = 0; fi < 8; ++fi)                                              \
      af[fi] = *(const short8*)(lds + hb_ + a_rd + fi * 1024);                  \
    _Pragma("unroll")                                                           \
    for (int fj = 0; fj < 4; ++fj)                                              \
      bf[fj] = *(const short8*)(lds + 65536 + hb_ + b_rd + fj * 1024);          \
    if (DOSTAGE) stageAB((T) + 1, (PH));                                        \
    __builtin_amdgcn_s_setprio(1);                                              \
    _Pragma("unroll")                                                           \
    for (int fi = 0; fi < 8; ++fi) {                                            \
      _Pragma("unroll")                                                         \
      for (int fj = 0; fj < 4; ++fj)                                            \
        acc[fi][fj] = __builtin_amdgcn_mfma_f32_16x16x32_bf16(af[fi], bf[fj],   \
                                                              acc[fi][fj], 0, 0, 0); \
    }                                                                           \
    __builtin_amdgcn_s_setprio(0);                                              \
  }

  stageAB(0, 0);
  stageAB(0, 1);
#pragma unroll 1
  for (int t = 0; t < NT - 1; ++t) {
    GPHASE(t, 0, "4", true);
    GPHASE(t, 1, "4", true);
  }
  GPHASE(NT - 1, 0, "4", false);
  GPHASE(NT - 1, 1, "0", false);
#undef GPHASE

  // epilogue: bf16 partial tile
  u16* Cp = Cpart + (size_t)z * ((size_t)M * N);
  const int rq = (lane >> 4) * 4;
  const int cq = lane & 15;
#pragma unroll
  for (int fi = 0; fi < 8; ++fi)
#pragma unroll
    for (int fj = 0; fj < 4; ++fj) {
      const int row = m0 + wr * 128 + fi * 16 + rq;
      const int col = n0 + wc * 64 + fj * 16 + cq;
#pragma unroll
      for (int q = 0; q < 4; ++q)
        Cp[(size_t)(row + q) * N + col] = f32_bf16(acc[fi][fj][q]);
    }
}

// ---------------- FC1 reduction: 7 bf16 partial slabs + bias + ReLU -> bf16 ---
__global__ __launch_bounds__(256) void reduce_bias7(
    const u16* __restrict__ P7, const float* __restrict__ bias,
    u16* __restrict__ out) {
  const int i4 = (blockIdx.x * 256 + threadIdx.x) * 4;  // 2M elems, grid 2048
  if (i4 >= 2097152) return;
  const int nb = i4 & 1023;
  float s0 = bias[nb], s1 = bias[nb + 1], s2 = bias[nb + 2], s3 = bias[nb + 3];
#pragma unroll
  for (int j = 0; j < 7; ++j) {
    const us4 v = *(const us4*)(P7 + (size_t)j * 2097152 + i4);
    s0 += bf16_f32(v.x); s1 += bf16_f32(v.y); s2 += bf16_f32(v.z); s3 += bf16_f32(v.w);
  }
  us4 o;
  o.x = f32_bf16(fmaxf(s0, 0.f)); o.y = f32_bf16(fmaxf(s1, 0.f));
  o.z = f32_bf16(fmaxf(s2, 0.f)); o.w = f32_bf16(fmaxf(s3, 0.f));
  *(us4*)(out + i4) = o;
}

// ---------------- old split-K BT-GEMM (f32 partials) for FC2 / proj -----------
template<int BM, int BN, int WGM, int WGN>
__global__ __launch_bounds__(256)
void gemm_bt_splitk(const u16* __restrict__ A, int lda,
                    const u16* __restrict__ B, int ldb,
                    float* __restrict__ Cpart, int M, int N, int Ksplit) {
  constexpr int BK = 64;
  constexpr int WM = BM / WGM, WN = BN / WGN;
  constexpr int FM = WM / 16, FN = WN / 16;
  constexpr int AITER = BM * BK / 2048;
  constexpr int BITER = BN * BK / 2048;
  __shared__ u16 Asm_[BM * BK];
  __shared__ u16 Bsm_[BN * BK];
  const int tid = threadIdx.x;
  const int wave = tid >> 6, lane = tid & 63;
  const int wr = wave / WGN, wc = wave % WGN;
  const int m0 = blockIdx.x * BM, n0 = blockIdx.y * BN;
  const int kbase0 = blockIdx.z * Ksplit;

  f32x4 acc[FM][FN];
#pragma unroll
  for (int i = 0; i < FM; ++i)
#pragma unroll
    for (int j = 0; j < FN; ++j)
      acc[i][j] = f32x4{0.0f, 0.0f, 0.0f, 0.0f};

  const int ar = tid >> 3;
  const int acsub = (tid & 7) * 8;
  const int fr = lane & 15;
  const int kq = (lane >> 4) * 8;

  for (int kt = 0; kt < Ksplit; kt += BK) {
    const int kb = kbase0 + kt;
#pragma unroll
    for (int it = 0; it < AITER; ++it) {
      const u16* src = A + (size_t)(m0 + it * 32 + ar) * lda + kb + acsub;
      load_lds16(src, (char*)Asm_ + it * 4096 + wave * 1024);
    }
#pragma unroll
    for (int it = 0; it < BITER; ++it) {
      const u16* src = B + (size_t)(n0 + it * 32 + ar) * ldb + kb + acsub;
      load_lds16(src, (char*)Bsm_ + it * 4096 + wave * 1024);
    }
    __syncthreads();
#pragma unroll
    for (int kk = 0; kk < BK; kk += 32) {
      short8 af[FM], bfr[FN];
#pragma unroll
      for (int i = 0; i < FM; ++i)
        af[i] = *(const short8*)(Asm_ + (wr * WM + i * 16 + fr) * BK + kk + kq);
#pragma unroll
      for (int j = 0; j < FN; ++j)
        bfr[j] = *(const short8*)(Bsm_ + (wc * WN + j * 16 + fr) * BK + kk + kq);
#pragma unroll
      for (int i = 0; i < FM; ++i)
#pragma unroll
        for (int j = 0; j < FN; ++j)
          acc[i][j] = __builtin_amdgcn_mfma_f32_16x16x32_bf16(af[i], bfr[j], acc[i][j], 0, 0, 0);
    }
    __syncthreads();
  }

  float* Cp = Cpart + (size_t)blockIdx.z * ((size_t)M * N);
  const int rq = (lane >> 4) * 4;
  const int cq = lane & 15;
#pragma unroll
  for (int i = 0; i < FM; ++i)
#pragma unroll
    for (int j = 0; j < FN; ++j) {
      const int row = m0 + wr * WM + i * 16 + rq;
      const int col = n0 + wc * WN + j * 16 + cq;
      float* o = Cp + (size_t)row * N + col;
#pragma unroll
      for (int q = 0; q < 4; ++q)
        o[(size_t)q * N] = acc[i][j][q];
    }
}

template<int S, bool RELU>
__global__ __launch_bounds__(256) void reduce_bias_bf16(
    const float* __restrict__ P, const float* __restrict__ bias,
    u16* __restrict__ out, int MN, int Nmask) {
  const int i = blockIdx.x * 256 + threadIdx.x;
  if (i >= MN) return;
  float s = bias[i & Nmask];
#pragma unroll
  for (int j = 0; j < S; ++j) s += P[(size_t)j * MN + i];
  if (RELU) s = fmaxf(s, 0.0f);
  out[i] = f32_bf16(s);
}

__global__ __launch_bounds__(256) void reduce_out(
    const float* __restrict__ P, const float* __restrict__ bp,
    float* __restrict__ out) {
  const int i = blockIdx.x * 256 + threadIdx.x;
  if (i >= 2048 * 93) return;
  const int mrow = i / 93;
  const int n = i - mrow * 93;
  float s = bp[n];
#pragma unroll
  for (int j = 0; j < 8; ++j) s += P[(size_t)j * (2048 * 96) + mrow * 96 + n];
  out[i] = s;
}

// ---------------- launch ------------------------------------------------------
extern "C" void kernel_launch(void* const* d_in, const int* in_sizes, int n_in,
                              void* d_out, int out_size, void* d_ws, size_t ws_size,
                              hipStream_t stream) {
  const float* p3   = (const float*)d_in[0];
  const float* p4   = (const float*)d_in[1];
  const float* p5   = (const float*)d_in[2];
  const float* bbox = (const float*)d_in[3];
  const int*   anc  = (const int*)d_in[4];
  const float* W1   = (const float*)d_in[5];
  const float* b1   = (const float*)d_in[6];
  const float* W2   = (const float*)d_in[7];
  const float* b2   = (const float*)d_in[8];
  const float* Wp   = (const float*)d_in[9];
  const float* bp   = (const float*)d_in[10];
  float* out = (float*)d_out;

  char* ws = (char*)d_ws;
  // Permanent: X [0, 51380224), W1b [51380224, 77070336)
  u16* X   = (u16*)(ws);
  u16* W1b = (u16*)(ws + 51380224);
  // Shared region R at 77070336 (size 44236800; footprint identical to round-2):
  //   Phase A (transpose+roi): t3|t4|t5 (44040192 B)
  //   Phase B (after roi): W2b|Wpb|H1|H2|{P7 bf16 29360128 / Pf f32 <=16777216}
  char* R = ws + 77070336;
  u16* t3  = (u16*)(R);
  u16* t4  = (u16*)(R + 33554432);
  u16* t5  = (u16*)(R + 41943040);
  u16* W2b = (u16*)(R);
  u16* Wpb = (u16*)(R + 2097152);
  u16* H1  = (u16*)(R + 2293760);
  u16* H2  = (u16*)(R + 6488064);
  u16*   P7 = (u16*)(R + 10682368);   // 7 x 2048x1024 bf16 (FC1 partials)
  float* Pf = (float*)(R + 10682368); // f32 partials for FC2/proj (reuse)
  (void)ws_size; (void)in_sizes; (void)n_in; (void)out_size;

  // Phase A: transpose feats to channels-last bf16, then ROI gather
  hipLaunchKernelGGL(transpose_feats, dim3(21504), dim3(256), 0, stream, p3, p4, p5, t3, t4, t5);
  hipLaunchKernelGGL(roi_pool2, dim3(2048), dim3(256), 0, stream, t3, t4, t5, bbox, anc, X);
  // Phase B: weights -> bf16
  hipLaunchKernelGGL(cvt_f32_bf16, dim3(12544), dim3(256), 0, stream, W1, W1b, 3211264);
  hipLaunchKernelGGL(cvt_f32_bf16, dim3(1024), dim3(256), 0, stream, W2, W2b, 262144);
  hipLaunchKernelGGL(cvt_wp, dim3(96), dim3(256), 0, stream, Wp, Wpb);
  // FC1: X @ W1^T — 256² phase-split pipeline, split-K=7 (NT=28 K-tiles each)
  hipLaunchKernelGGL((gemm8_bt<28>), dim3(224), dim3(512), 0, stream,
                     X, 12544, W1b, 12544, P7, 2048, 1024, 8, 4);
  hipLaunchKernelGGL(reduce_bias7, dim3(2048), dim3(256), 0, stream, P7, b1, H1);
  // FC2: H1 @ W2^T, split-K=2 (old structure)
  hipLaunchKernelGGL((gemm_bt_splitk<128,128,2,2>), dim3(16, 8, 2), dim3(256), 0, stream,
                     H1, 1024, W2b, 1024, Pf, 2048, 1024, 512);
  hipLaunchKernelGGL((reduce_bias_bf16<2,true>), dim3(8192), dim3(256), 0, stream,
                     Pf, b2, H2, 2048 * 1024, 1023);
  // proj: H2 @ Wp^T (N padded to 96), split-K=8
  hipLaunchKernelGGL((gemm_bt_splitk<128,96,4,1>), dim3(16, 1, 8), dim3(256), 0, stream,
                     H2, 1024, Wpb, 1024, Pf, 2048, 96, 128);
  hipLaunchKernelGGL(reduce_out, dim3(744), dim3(256), 0, stream, Pf, bp, out);
}

// Round 7
// 175.595 us; speedup vs baseline: 2.8184x; 1.0995x over previous
//
#include <hip/hip_runtime.h>
#include <hip/hip_bf16.h>

typedef unsigned short u16;
typedef __attribute__((ext_vector_type(8))) short short8;
typedef __attribute__((ext_vector_type(4))) float f32x4;
typedef __attribute__((ext_vector_type(4))) unsigned short us4;
typedef __attribute__((ext_vector_type(8))) _Float16 h8;

__device__ __forceinline__ u16 f32_bf16(float f) {
  union { float f; unsigned int u; } v; v.f = f;
  unsigned int r = v.u + 0x7fffu + ((v.u >> 16) & 1u);  // round-to-nearest-even
  return (u16)(r >> 16);
}
__device__ __forceinline__ float bf16_f32(u16 h) {
  union { unsigned int u; float f; } v; v.u = ((unsigned int)h) << 16; return v.f;
}
__device__ __forceinline__ u16 f32_f16(float f) {
  union { _Float16 h; u16 u; } v; v.h = (_Float16)f; return v.u;
}
__device__ __forceinline__ h8 splat8(float f) {
  _Float16 h = (_Float16)f;
  h8 r = {h, h, h, h, h, h, h, h};
  return r;
}

__device__ __forceinline__ void load_lds16(const void* g, void* l) {
  __builtin_amdgcn_global_load_lds((const __attribute__((address_space(1))) unsigned int*)g,
                                   (__attribute__((address_space(3))) unsigned int*)l,
                                   16, 0, 0);
}

// ---------------- generic f32 -> bf16 (vectorized ×4) -------------------------
__global__ __launch_bounds__(256) void cvt_f32_bf16(
    const float* __restrict__ src, u16* __restrict__ dst, int n4) {
  int i = blockIdx.x * 256 + threadIdx.x;
  if (i >= n4) return;
  const float4 v = ((const float4*)src)[i];
  unsigned long long pk = (unsigned long long)f32_bf16(v.x)
                        | ((unsigned long long)f32_bf16(v.y) << 16)
                        | ((unsigned long long)f32_bf16(v.z) << 32)
                        | ((unsigned long long)f32_bf16(v.w) << 48);
  ((unsigned long long*)dst)[i] = pk;
}

// Wp: 93x1024 f32 -> 96x1024 bf16 zero-padded
__global__ __launch_bounds__(256) void cvt_wp(
    const float* __restrict__ src, u16* __restrict__ dst) {
  int i = blockIdx.x * 256 + threadIdx.x;
  if (i >= 24576) return;
  int e = i * 4;
  float4 v = (e < 95232) ? ((const float4*)src)[i] : float4{0.f, 0.f, 0.f, 0.f};
  unsigned long long pk = (unsigned long long)f32_bf16(v.x)
                        | ((unsigned long long)f32_bf16(v.y) << 16)
                        | ((unsigned long long)f32_bf16(v.z) << 32)
                        | ((unsigned long long)f32_bf16(v.w) << 48);
  ((unsigned long long*)dst)[i] = pk;
}

// ---------------- feature transpose: [B,C,S,S] f32 -> [B,S,S,C] fp16 ----------
__global__ __launch_bounds__(256) void transpose_feats(
    const float* __restrict__ p3, const float* __restrict__ p4, const float* __restrict__ p5,
    u16* __restrict__ t3, u16* __restrict__ t4, u16* __restrict__ t5) {
  const int bid = blockIdx.x;
  const float* src; u16* dst; int S, tile;
  if (bid < 16384)      { src = p3; dst = t3; S = 128; tile = bid; }
  else if (bid < 20480) { src = p4; dst = t4; S = 64;  tile = bid - 16384; }
  else                  { src = p5; dst = t5; S = 32;  tile = bid - 20480; }
  const int cchunk = tile & 3;
  const int fp0 = (tile >> 2) * 16;
  const int SS = S * S;
  const int b = fp0 / SS;
  const int pimg = fp0 - b * SS;
  __shared__ __align__(16) u16 lds[16 * 72];
  const int t = threadIdx.x;
  {
    const int cl = t >> 2, xv = t & 3;
    const int c = cchunk * 64 + cl;
    const float4 v = *(const float4*)(src + (size_t)(b * 256 + c) * SS + pimg + xv * 4);
    lds[(xv * 4 + 0) * 72 + cl] = f32_f16(v.x);
    lds[(xv * 4 + 1) * 72 + cl] = f32_f16(v.y);
    lds[(xv * 4 + 2) * 72 + cl] = f32_f16(v.z);
    lds[(xv * 4 + 3) * 72 + cl] = f32_f16(v.w);
  }
  __syncthreads();
  {
    const int xl = t >> 4, cg = (t & 15) * 4;
    const us4 h = *(const us4*)&lds[xl * 72 + cg];
    *(us4*)(dst + (size_t)(fp0 + xl) * 256 + cchunk * 64 + cg) = h;
  }
}

// ------- ROI align v3: fp16 channels-last gather, packed-fp16 accumulate ------
// 32 lanes x 8ch cover 256 channels; 2 positions per wave per iteration.
__global__ __launch_bounds__(256) void roi_pool3(
    const u16* __restrict__ t3, const u16* __restrict__ t4, const u16* __restrict__ t5,
    const float* __restrict__ bbox, const int* __restrict__ anchor,
    u16* __restrict__ X) {
  const int m = blockIdx.x;
  const int b = m >> 9;
  const int lvl = anchor[m] / 3;
  const u16* ft; int S; float scale;
  if (lvl == 0)      { ft = t3; S = 128; scale = 0.125f;   }
  else if (lvl == 1) { ft = t4; S = 64;  scale = 0.0625f;  }
  else               { ft = t5; S = 32;  scale = 0.03125f; }
  ft += (size_t)b * S * S * 256;
  const float* bx = bbox + (size_t)m * 4;
  const float x1 = bx[0] * scale - 0.5f;
  const float y1 = bx[1] * scale - 0.5f;
  const float bw = (bx[2] * scale - 0.5f - x1) * (1.0f / 7.0f);
  const float bh = (bx[3] * scale - 0.5f - y1) * (1.0f / 7.0f);
  const float fS = (float)S;

  __shared__ __align__(16) u16 xs[12544];
  const int wave = threadIdx.x >> 6, lane = threadIdx.x & 63;
  const int l = lane & 31, h = lane >> 5;
  const int cbase = l * 8;

#pragma unroll 1
  for (int it = 0; it < 7; ++it) {
    const int p = it * 8 + wave * 2 + h;
    if (p < 49) {
      const int py = p / 7, px = p - py * 7;
      h8 acc = splat8(0.0f);
#pragma unroll
      for (int sy = 0; sy < 2; ++sy) {
        const float y = y1 + bh * ((float)py + (sy ? 0.75f : 0.25f));
        const float my = (y >= -1.0f && y <= fS) ? 1.0f : 0.0f;
        const float cy = fminf(fmaxf(y, 0.0f), fS - 1.0f);
        const int y0 = (int)cy;
        const float ly = cy - (float)y0;
        const float hy = 1.0f - ly;
        const int y1i = (y0 + 1 < S) ? y0 + 1 : S - 1;
#pragma unroll
        for (int sx = 0; sx < 2; ++sx) {
          const float x = x1 + bw * ((float)px + (sx ? 0.75f : 0.25f));
          const float mx = (x >= -1.0f && x <= fS) ? 1.0f : 0.0f;
          const float cx = fminf(fmaxf(x, 0.0f), fS - 1.0f);
          const int x0 = (int)cx;
          const float lx = cx - (float)x0;
          const float hx = 1.0f - lx;
          const int x1i = (x0 + 1 < S) ? x0 + 1 : S - 1;
          const h8 f00 = *(const h8*)(ft + (size_t)(y0  * S + x0 ) * 256 + cbase);
          const h8 f01 = *(const h8*)(ft + (size_t)(y0  * S + x1i) * 256 + cbase);
          const h8 f10 = *(const h8*)(ft + (size_t)(y1i * S + x0 ) * 256 + cbase);
          const h8 f11 = *(const h8*)(ft + (size_t)(y1i * S + x1i) * 256 + cbase);
          const float msk = my * mx;
          acc += f00 * splat8(hy * hx * msk);
          acc += f01 * splat8(hy * lx * msk);
          acc += f10 * splat8(ly * hx * msk);
          acc += f11 * splat8(ly * lx * msk);
        }
      }
#pragma unroll
      for (int i = 0; i < 8; ++i)
        xs[(cbase + i) * 49 + p] = f32_bf16((float)acc[i] * 0.25f);
    }
  }
  __syncthreads();
  uint4* dst = (uint4*)(X + (size_t)m * 12544);
  const uint4* srcl = (const uint4*)xs;
  for (int i = threadIdx.x; i < 1568; i += 256) dst[i] = srcl[i];
}

// ============ 256x256 phase-split pipelined BT-GEMM (bf16 partials out) =======
// 8 waves (2M x 4N), BK=64 in two K-half phases. Per phase:
//   vmcnt(4) -> s_barrier -> sched_barrier -> 12 ds_read_b128 ->
//   stage K-half of tile t+1 (4 global_load_lds) -> setprio(1) 32 MFMA setprio(0)
// LDS 128 KiB: A/B x dbuf x khalf, each 16 KiB = 128 row-pairs x 128B,
// XOR-swizzled (byte ^= (rowpair&7)<<4) on BOTH global source and LDS read.
// Runtime K-range: uneven split-K (z<4: 25 K-tiles, else 24).
__global__ __launch_bounds__(512, 2)
void gemm8_bt(const u16* __restrict__ A, int lda,
              const u16* __restrict__ B, int ldb,
              u16* __restrict__ Cpart, int M, int N,
              int mb, int nb) {
  __shared__ __align__(16) char lds[131072];
  const int tid = threadIdx.x;
  const int wave = tid >> 6, lane = tid & 63;
  const int wr = wave >> 2, wc = wave & 3;

  const int G = gridDim.x;
  const int bid = blockIdx.x;
  const int swz = (bid & 7) * (G >> 3) + (bid >> 3);
  const int x = swz % mb;
  const int rest = swz / mb;
  const int y = rest % nb;
  const int z = rest / nb;
  const int m0 = x * 256, n0 = y * 256;
  const int nt = 24 + (z < 4 ? 1 : 0);
  const int kb0 = (z * 24 + (z < 4 ? z : 4)) * 64;

  const int sb = ((lane & 7) ^ (lane >> 3)) << 4;
  const int rowb2 = 2 * (wave * 8 + (lane >> 3)) + (sb >> 6);
  const int keloff = (sb & 63) >> 1;

  const int frow = lane & 15;
  const int rh = frow >> 1;
  const int swb = ((((frow & 1) << 6) | ((lane >> 4) << 4))) ^ (rh << 4);
  const int a_rd = wr * 8192 + rh * 128 + swb;
  const int b_rd = wc * 4096 + rh * 128 + swb;

  f32x4 acc[8][4];
#pragma unroll
  for (int i = 0; i < 8; ++i)
#pragma unroll
    for (int j = 0; j < 4; ++j)
      acc[i][j] = f32x4{0.f, 0.f, 0.f, 0.f};

  auto stageAB = [&](int tile, int ph) {
    const int dst = ((tile & 1) * 2 + ph) * 16384;
    const int kel = kb0 + tile * 64 + ph * 32 + keloff;
#pragma unroll
    for (int i = 0; i < 2; ++i) {
      const u16* srcA = A + (size_t)(m0 + i * 128 + rowb2) * lda + kel;
      load_lds16(srcA, lds + dst + i * 8192 + wave * 1024);
    }
#pragma unroll
    for (int i = 0; i < 2; ++i) {
      const u16* srcB = B + (size_t)(n0 + i * 128 + rowb2) * ldb + kel;
      load_lds16(srcB, lds + 65536 + dst + i * 8192 + wave * 1024);
    }
  };

#define GPHASE(T, PH, VW, DOSTAGE)                                              \
  {                                                                             \
    asm volatile("s_waitcnt vmcnt(" VW ")" ::: "memory");                       \
    __builtin_amdgcn_s_barrier();                                               \
    __builtin_amdgcn_sched_barrier(0);                                          \
    const int hb_ = (((T) & 1) * 2 + (PH)) * 16384;                             \
    short8 af[8], bf[4];                                                        \
    _Pragma("unroll")                                                           \
    for (int fi = 0; fi < 8; ++fi)                                              \
      af[fi] = *(const short8*)(lds + hb_ + a_rd + fi * 1024);                  \
    _Pragma("unroll")                                                           \
    for (int fj = 0; fj < 4; ++fj)                                              \
      bf[fj] = *(const short8*)(lds + 65536 + hb_ + b_rd + fj * 1024);          \
    if (DOSTAGE) stageAB((T) + 1, (PH));                                        \
    __builtin_amdgcn_s_setprio(1);                                              \
    _Pragma("unroll")                                                           \
    for (int fi = 0; fi < 8; ++fi) {                                            \
      _Pragma("unroll")                                                         \
      for (int fj = 0; fj < 4; ++fj)                                            \
        acc[fi][fj] = __builtin_amdgcn_mfma_f32_16x16x32_bf16(af[fi], bf[fj],   \
                                                              acc[fi][fj], 0, 0, 0); \
    }                                                                           \
    __builtin_amdgcn_s_setprio(0);                                              \
  }

  stageAB(0, 0);
  stageAB(0, 1);
#pragma unroll 1
  for (int t = 0; t < nt - 1; ++t) {
    GPHASE(t, 0, "4", true);
    GPHASE(t, 1, "4", true);
  }
  GPHASE(nt - 1, 0, "4", false);
  GPHASE(nt - 1, 1, "0", false);
#undef GPHASE

  u16* Cp = Cpart + (size_t)z * ((size_t)M * N);
  const int rq = (lane >> 4) * 4;
  const int cq = lane & 15;
#pragma unroll
  for (int fi = 0; fi < 8; ++fi)
#pragma unroll
    for (int fj = 0; fj < 4; ++fj) {
      const int row = m0 + wr * 128 + fi * 16 + rq;
      const int col = n0 + wc * 64 + fj * 16 + cq;
#pragma unroll
      for (int q = 0; q < 4; ++q)
        Cp[(size_t)(row + q) * N + col] = f32_bf16(acc[fi][fj][q]);
    }
}

// ---------------- FC1 reduction: 8 bf16 partial slabs + bias + ReLU -> bf16 ---
__global__ __launch_bounds__(256) void reduce_bias8(
    const u16* __restrict__ P8, const float* __restrict__ bias,
    u16* __restrict__ out) {
  const int i4 = (blockIdx.x * 256 + threadIdx.x) * 4;
  if (i4 >= 2097152) return;
  const int nb = i4 & 1023;
  float s0 = bias[nb], s1 = bias[nb + 1], s2 = bias[nb + 2], s3 = bias[nb + 3];
#pragma unroll
  for (int j = 0; j < 8; ++j) {
    const us4 v = *(const us4*)(P8 + (size_t)j * 2097152 + i4);
    s0 += bf16_f32(v.x); s1 += bf16_f32(v.y); s2 += bf16_f32(v.z); s3 += bf16_f32(v.w);
  }
  us4 o;
  o.x = f32_bf16(fmaxf(s0, 0.f)); o.y = f32_bf16(fmaxf(s1, 0.f));
  o.z = f32_bf16(fmaxf(s2, 0.f)); o.w = f32_bf16(fmaxf(s3, 0.f));
  *(us4*)(out + i4) = o;
}

// ---------------- old split-K BT-GEMM (f32 partials) for FC2 / proj -----------
template<int BM, int BN, int WGM, int WGN>
__global__ __launch_bounds__(256)
void gemm_bt_splitk(const u16* __restrict__ A, int lda,
                    const u16* __restrict__ B, int ldb,
                    float* __restrict__ Cpart, int M, int N, int Ksplit) {
  constexpr int BK = 64;
  constexpr int WM = BM / WGM, WN = BN / WGN;
  constexpr int FM = WM / 16, FN = WN / 16;
  constexpr int AITER = BM * BK / 2048;
  constexpr int BITER = BN * BK / 2048;
  __shared__ u16 Asm_[BM * BK];
  __shared__ u16 Bsm_[BN * BK];
  const int tid = threadIdx.x;
  const int wave = tid >> 6, lane = tid & 63;
  const int wr = wave / WGN, wc = wave % WGN;
  const int m0 = blockIdx.x * BM, n0 = blockIdx.y * BN;
  const int kbase0 = blockIdx.z * Ksplit;

  f32x4 acc[FM][FN];
#pragma unroll
  for (int i = 0; i < FM; ++i)
#pragma unroll
    for (int j = 0; j < FN; ++j)
      acc[i][j] = f32x4{0.0f, 0.0f, 0.0f, 0.0f};

  const int ar = tid >> 3;
  const int acsub = (tid & 7) * 8;
  const int fr = lane & 15;
  const int kq = (lane >> 4) * 8;

  for (int kt = 0; kt < Ksplit; kt += BK) {
    const int kb = kbase0 + kt;
#pragma unroll
    for (int it = 0; it < AITER; ++it) {
      const u16* src = A + (size_t)(m0 + it * 32 + ar) * lda + kb + acsub;
      load_lds16(src, (char*)Asm_ + it * 4096 + wave * 1024);
    }
#pragma unroll
    for (int it = 0; it < BITER; ++it) {
      const u16* src = B + (size_t)(n0 + it * 32 + ar) * ldb + kb + acsub;
      load_lds16(src, (char*)Bsm_ + it * 4096 + wave * 1024);
    }
    __syncthreads();
#pragma unroll
    for (int kk = 0; kk < BK; kk += 32) {
      short8 af[FM], bfr[FN];
#pragma unroll
      for (int i = 0; i < FM; ++i)
        af[i] = *(const short8*)(Asm_ + (wr * WM + i * 16 + fr) * BK + kk + kq);
#pragma unroll
      for (int j = 0; j < FN; ++j)
        bfr[j] = *(const short8*)(Bsm_ + (wc * WN + j * 16 + fr) * BK + kk + kq);
#pragma unroll
      for (int i = 0; i < FM; ++i)
#pragma unroll
        for (int j = 0; j < FN; ++j)
          acc[i][j] = __builtin_amdgcn_mfma_f32_16x16x32_bf16(af[i], bfr[j], acc[i][j], 0, 0, 0);
    }
    __syncthreads();
  }

  float* Cp = Cpart + (size_t)blockIdx.z * ((size_t)M * N);
  const int rq = (lane >> 4) * 4;
  const int cq = lane & 15;
#pragma unroll
  for (int i = 0; i < FM; ++i)
#pragma unroll
    for (int j = 0; j < FN; ++j) {
      const int row = m0 + wr * WM + i * 16 + rq;
      const int col = n0 + wc * WN + j * 16 + cq;
      float* o = Cp + (size_t)row * N + col;
#pragma unroll
      for (int q = 0; q < 4; ++q)
        o[(size_t)q * N] = acc[i][j][q];
    }
}

template<int S, bool RELU>
__global__ __launch_bounds__(256) void reduce_bias_bf16(
    const float* __restrict__ P, const float* __restrict__ bias,
    u16* __restrict__ out, int MN, int Nmask) {
  const int i = blockIdx.x * 256 + threadIdx.x;
  if (i >= MN) return;
  float s = bias[i & Nmask];
#pragma unroll
  for (int j = 0; j < S; ++j) s += P[(size_t)j * MN + i];
  if (RELU) s = fmaxf(s, 0.0f);
  out[i] = f32_bf16(s);
}

__global__ __launch_bounds__(256) void reduce_out(
    const float* __restrict__ P, const float* __restrict__ bp,
    float* __restrict__ out) {
  const int i = blockIdx.x * 256 + threadIdx.x;
  if (i >= 2048 * 93) return;
  const int mrow = i / 93;
  const int n = i - mrow * 93;
  float s = bp[n];
#pragma unroll
  for (int j = 0; j < 8; ++j) s += P[(size_t)j * (2048 * 96) + mrow * 96 + n];
  out[i] = s;
}

// ---------------- launch ------------------------------------------------------
extern "C" void kernel_launch(void* const* d_in, const int* in_sizes, int n_in,
                              void* d_out, int out_size, void* d_ws, size_t ws_size,
                              hipStream_t stream) {
  const float* p3   = (const float*)d_in[0];
  const float* p4   = (const float*)d_in[1];
  const float* p5   = (const float*)d_in[2];
  const float* bbox = (const float*)d_in[3];
  const int*   anc  = (const int*)d_in[4];
  const float* W1   = (const float*)d_in[5];
  const float* b1   = (const float*)d_in[6];
  const float* W2   = (const float*)d_in[7];
  const float* b2   = (const float*)d_in[8];
  const float* Wp   = (const float*)d_in[9];
  const float* bp   = (const float*)d_in[10];
  float* out = (float*)d_out;

  char* ws = (char*)d_ws;
  // Permanent: X [0, 51380224), W1b [51380224, 77070336)
  u16* X   = (u16*)(ws);
  u16* W1b = (u16*)(ws + 51380224);
  // Shared region R at 77070336 (size 44236800; total 121307136 B, proven fit):
  //   Phase A (transpose+roi): t3|t4|t5 fp16 (44040192 B)
  //   Phase B (after roi): W2b|Wpb|H1|H2|{P8 bf16 33554432 / Pf f32 <=16777216}
  char* R = ws + 77070336;
  u16* t3  = (u16*)(R);
  u16* t4  = (u16*)(R + 33554432);
  u16* t5  = (u16*)(R + 41943040);
  u16* W2b = (u16*)(R);
  u16* Wpb = (u16*)(R + 2097152);
  u16* H1  = (u16*)(R + 2293760);
  u16* H2  = (u16*)(R + 6488064);
  u16*   P8 = (u16*)(R + 10682368);   // 8 x 2048x1024 bf16 (FC1 partials)
  float* Pf = (float*)(R + 10682368); // f32 partials for FC2/proj (reuse)
  (void)ws_size; (void)in_sizes; (void)n_in; (void)out_size;

  // Phase A: transpose feats to channels-last fp16, then ROI gather
  hipLaunchKernelGGL(transpose_feats, dim3(21504), dim3(256), 0, stream, p3, p4, p5, t3, t4, t5);
  hipLaunchKernelGGL(roi_pool3, dim3(2048), dim3(256), 0, stream, t3, t4, t5, bbox, anc, X);
  // Phase B: weights -> bf16
  hipLaunchKernelGGL(cvt_f32_bf16, dim3(12544), dim3(256), 0, stream, W1, W1b, 3211264);
  hipLaunchKernelGGL(cvt_f32_bf16, dim3(1024), dim3(256), 0, stream, W2, W2b, 262144);
  hipLaunchKernelGGL(cvt_wp, dim3(96), dim3(256), 0, stream, Wp, Wpb);
  // FC1: X @ W1^T — 256² phase-split pipeline, uneven split-K=8 (25/24 K-tiles)
  hipLaunchKernelGGL(gemm8_bt, dim3(256), dim3(512), 0, stream,
                     X, 12544, W1b, 12544, P8, 2048, 1024, 8, 4);
  hipLaunchKernelGGL(reduce_bias8, dim3(2048), dim3(256), 0, stream, P8, b1, H1);
  // FC2: H1 @ W2^T, split-K=2 (old structure)
  hipLaunchKernelGGL((gemm_bt_splitk<128,128,2,2>), dim3(16, 8, 2), dim3(256), 0, stream,
                     H1, 1024, W2b, 1024, Pf, 2048, 1024, 512);
  hipLaunchKernelGGL((reduce_bias_bf16<2,true>), dim3(8192), dim3(256), 0, stream,
                     Pf, b2, H2, 2048 * 1024, 1023);
  // proj: H2 @ Wp^T (N padded to 96), split-K=8
  hipLaunchKernelGGL((gemm_bt_splitk<128,96,4,1>), dim3(16, 1, 8), dim3(256), 0, stream,
                     H2, 1024, Wpb, 1024, Pf, 2048, 96, 128);
  hipLaunchKernelGGL(reduce_out, dim3(744), dim3(256), 0, stream, Pf, bp, out);
}

// Round 9
// 172.071 us; speedup vs baseline: 2.8761x; 1.0205x over previous
//
#include <hip/hip_runtime.h>
#include <hip/hip_bf16.h>

typedef unsigned short u16;
typedef __attribute__((ext_vector_type(8))) short short8;
typedef __attribute__((ext_vector_type(4))) float f32x4;
typedef __attribute__((ext_vector_type(4))) unsigned short us4;
typedef __attribute__((ext_vector_type(8))) _Float16 h8;

__device__ __forceinline__ u16 f32_bf16(float f) {
  union { float f; unsigned int u; } v; v.f = f;
  unsigned int r = v.u + 0x7fffu + ((v.u >> 16) & 1u);  // round-to-nearest-even
  return (u16)(r >> 16);
}
__device__ __forceinline__ float bf16_f32(u16 h) {
  union { unsigned int u; float f; } v; v.u = ((unsigned int)h) << 16; return v.f;
}
__device__ __forceinline__ u16 f32_f16(float f) {
  union { _Float16 h; u16 u; } v; v.h = (_Float16)f; return v.u;
}
__device__ __forceinline__ h8 splat8(float f) {
  _Float16 h = (_Float16)f;
  h8 r = {h, h, h, h, h, h, h, h};
  return r;
}

__device__ __forceinline__ void load_lds16(const void* g, void* l) {
  __builtin_amdgcn_global_load_lds((const __attribute__((address_space(1))) unsigned int*)g,
                                   (__attribute__((address_space(3))) unsigned int*)l,
                                   16, 0, 0);
}

// ------------- merged weight conversion: W1 | W2 | Wp(pad 96) -> bf16 ---------
__global__ __launch_bounds__(256) void cvt_all(
    const float* __restrict__ W1, const float* __restrict__ W2,
    const float* __restrict__ Wp,
    u16* __restrict__ W1b, u16* __restrict__ W2b, u16* __restrict__ Wpb) {
  const int bid = blockIdx.x;
  const float* src; u16* dst; int i;
  if (bid < 12544)      { i = bid * 256 + threadIdx.x; src = W1; dst = W1b; }
  else if (bid < 13568) { i = (bid - 12544) * 256 + threadIdx.x; src = W2; dst = W2b; }
  else {
    i = (bid - 13568) * 256 + threadIdx.x;
    float4 v = (i * 4 < 95232) ? ((const float4*)Wp)[i] : float4{0.f, 0.f, 0.f, 0.f};
    unsigned long long pk = (unsigned long long)f32_bf16(v.x)
                          | ((unsigned long long)f32_bf16(v.y) << 16)
                          | ((unsigned long long)f32_bf16(v.z) << 32)
                          | ((unsigned long long)f32_bf16(v.w) << 48);
    ((unsigned long long*)Wpb)[i] = pk;
    return;
  }
  const float4 v = ((const float4*)src)[i];
  unsigned long long pk = (unsigned long long)f32_bf16(v.x)
                        | ((unsigned long long)f32_bf16(v.y) << 16)
                        | ((unsigned long long)f32_bf16(v.z) << 32)
                        | ((unsigned long long)f32_bf16(v.w) << 48);
  ((unsigned long long*)dst)[i] = pk;
}

// ---------------- feature transpose: [B,C,S,S] f32 -> [B,S,S,C] fp16 ----------
__global__ __launch_bounds__(256) void transpose_feats(
    const float* __restrict__ p3, const float* __restrict__ p4, const float* __restrict__ p5,
    u16* __restrict__ t3, u16* __restrict__ t4, u16* __restrict__ t5) {
  const int bid = blockIdx.x;
  const float* src; u16* dst; int S, tile;
  if (bid < 16384)      { src = p3; dst = t3; S = 128; tile = bid; }
  else if (bid < 20480) { src = p4; dst = t4; S = 64;  tile = bid - 16384; }
  else                  { src = p5; dst = t5; S = 32;  tile = bid - 20480; }
  const int cchunk = tile & 3;
  const int fp0 = (tile >> 2) * 16;
  const int SS = S * S;
  const int b = fp0 / SS;
  const int pimg = fp0 - b * SS;
  __shared__ __align__(16) u16 lds[16 * 72];
  const int t = threadIdx.x;
  {
    const int cl = t >> 2, xv = t & 3;
    const int c = cchunk * 64 + cl;
    const float4 v = *(const float4*)(src + (size_t)(b * 256 + c) * SS + pimg + xv * 4);
    lds[(xv * 4 + 0) * 72 + cl] = f32_f16(v.x);
    lds[(xv * 4 + 1) * 72 + cl] = f32_f16(v.y);
    lds[(xv * 4 + 2) * 72 + cl] = f32_f16(v.z);
    lds[(xv * 4 + 3) * 72 + cl] = f32_f16(v.w);
  }
  __syncthreads();
  {
    const int xl = t >> 4, cg = (t & 15) * 4;
    const us4 h = *(const us4*)&lds[xl * 72 + cg];
    *(us4*)(dst + (size_t)(fp0 + xl) * 256 + cchunk * 64 + cg) = h;
  }
}

// ------- ROI align v3: fp16 channels-last gather, packed-fp16 accumulate ------
__global__ __launch_bounds__(256) void roi_pool3(
    const u16* __restrict__ t3, const u16* __restrict__ t4, const u16* __restrict__ t5,
    const float* __restrict__ bbox, const int* __restrict__ anchor,
    u16* __restrict__ X) {
  const int m = blockIdx.x;
  const int b = m >> 9;
  const int lvl = anchor[m] / 3;
  const u16* ft; int S; float scale;
  if (lvl == 0)      { ft = t3; S = 128; scale = 0.125f;   }
  else if (lvl == 1) { ft = t4; S = 64;  scale = 0.0625f;  }
  else               { ft = t5; S = 32;  scale = 0.03125f; }
  ft += (size_t)b * S * S * 256;
  const float* bx = bbox + (size_t)m * 4;
  const float x1 = bx[0] * scale - 0.5f;
  const float y1 = bx[1] * scale - 0.5f;
  const float bw = (bx[2] * scale - 0.5f - x1) * (1.0f / 7.0f);
  const float bh = (bx[3] * scale - 0.5f - y1) * (1.0f / 7.0f);
  const float fS = (float)S;

  __shared__ __align__(16) u16 xs[12544];
  const int wave = threadIdx.x >> 6, lane = threadIdx.x & 63;
  const int l = lane & 31, h = lane >> 5;
  const int cbase = l * 8;

#pragma unroll 1
  for (int it = 0; it < 7; ++it) {
    const int p = it * 8 + wave * 2 + h;
    if (p < 49) {
      const int py = p / 7, px = p - py * 7;
      h8 acc = splat8(0.0f);
#pragma unroll
      for (int sy = 0; sy < 2; ++sy) {
        const float y = y1 + bh * ((float)py + (sy ? 0.75f : 0.25f));
        const float my = (y >= -1.0f && y <= fS) ? 1.0f : 0.0f;
        const float cy = fminf(fmaxf(y, 0.0f), fS - 1.0f);
        const int y0 = (int)cy;
        const float ly = cy - (float)y0;
        const float hy = 1.0f - ly;
        const int y1i = (y0 + 1 < S) ? y0 + 1 : S - 1;
#pragma unroll
        for (int sx = 0; sx < 2; ++sx) {
          const float x = x1 + bw * ((float)px + (sx ? 0.75f : 0.25f));
          const float mx = (x >= -1.0f && x <= fS) ? 1.0f : 0.0f;
          const float cx = fminf(fmaxf(x, 0.0f), fS - 1.0f);
          const int x0 = (int)cx;
          const float lx = cx - (float)x0;
          const float hx = 1.0f - lx;
          const int x1i = (x0 + 1 < S) ? x0 + 1 : S - 1;
          const h8 f00 = *(const h8*)(ft + (size_t)(y0  * S + x0 ) * 256 + cbase);
          const h8 f01 = *(const h8*)(ft + (size_t)(y0  * S + x1i) * 256 + cbase);
          const h8 f10 = *(const h8*)(ft + (size_t)(y1i * S + x0 ) * 256 + cbase);
          const h8 f11 = *(const h8*)(ft + (size_t)(y1i * S + x1i) * 256 + cbase);
          const float msk = my * mx;
          acc += f00 * splat8(hy * hx * msk);
          acc += f01 * splat8(hy * lx * msk);
          acc += f10 * splat8(ly * hx * msk);
          acc += f11 * splat8(ly * lx * msk);
        }
      }
#pragma unroll
      for (int i = 0; i < 8; ++i)
        xs[(cbase + i) * 49 + p] = f32_bf16((float)acc[i] * 0.25f);
    }
  }
  __syncthreads();
  uint4* dst = (uint4*)(X + (size_t)m * 12544);
  const uint4* srcl = (const uint4*)xs;
  for (int i = threadIdx.x; i < 1568; i += 256) dst[i] = srcl[i];
}

// ============ 256x256 phase-split pipelined BT-GEMM (bf16 partials out) =======
// VERIFIED round-7 schedule. 8 waves (2M x 4N), BK=64 in two K-half phases:
//   vmcnt(4) -> s_barrier -> sched_barrier -> stage(t+1,ph) -> 12 ds_read_b128
//   -> setprio(1) 32 MFMA setprio(0)
// (stage moved before ds_reads: same barrier interval & vmcnt counts, earlier
// global-load issue.) LDS 128 KiB, st-swizzle byte^=(rowpair&7)<<4 on BOTH
// global source and LDS read. Uneven split-K=8 (z<4: 25 K-tiles, else 24).
__global__ __launch_bounds__(512, 2)
void gemm8_bt(const u16* __restrict__ A, int lda,
              const u16* __restrict__ B, int ldb,
              u16* __restrict__ Cpart, int M, int N,
              int mb, int nb) {
  __shared__ __align__(16) char lds[131072];
  const int tid = threadIdx.x;
  const int wave = tid >> 6, lane = tid & 63;
  const int wr = wave >> 2, wc = wave & 3;

  const int G = gridDim.x;
  const int bid = blockIdx.x;
  const int swz = (bid & 7) * (G >> 3) + (bid >> 3);
  const int x = swz % mb;
  const int rest = swz / mb;
  const int y = rest % nb;
  const int z = rest / nb;
  const int m0 = x * 256, n0 = y * 256;
  const int nt = 24 + (z < 4 ? 1 : 0);
  const int kb0 = (z * 24 + (z < 4 ? z : 4)) * 64;

  const int sb = ((lane & 7) ^ (lane >> 3)) << 4;
  const int rowb2 = 2 * (wave * 8 + (lane >> 3)) + (sb >> 6);
  const int keloff = (sb & 63) >> 1;

  const int frow = lane & 15;
  const int rh = frow >> 1;
  const int swb = ((((frow & 1) << 6) | ((lane >> 4) << 4))) ^ (rh << 4);
  const int a_rd = wr * 8192 + rh * 128 + swb;
  const int b_rd = wc * 4096 + rh * 128 + swb;

  f32x4 acc[8][4];
#pragma unroll
  for (int i = 0; i < 8; ++i)
#pragma unroll
    for (int j = 0; j < 4; ++j)
      acc[i][j] = f32x4{0.f, 0.f, 0.f, 0.f};

  auto stageAB = [&](int tile, int ph) {
    const int dst = ((tile & 1) * 2 + ph) * 16384;
    const int kel = kb0 + tile * 64 + ph * 32 + keloff;
#pragma unroll
    for (int i = 0; i < 2; ++i) {
      const u16* srcA = A + (size_t)(m0 + i * 128 + rowb2) * lda + kel;
      load_lds16(srcA, lds + dst + i * 8192 + wave * 1024);
    }
#pragma unroll
    for (int i = 0; i < 2; ++i) {
      const u16* srcB = B + (size_t)(n0 + i * 128 + rowb2) * ldb + kel;
      load_lds16(srcB, lds + 65536 + dst + i * 8192 + wave * 1024);
    }
  };

#define GPHASE(T, PH, VW, DOSTAGE)                                              \
  {                                                                             \
    asm volatile("s_waitcnt vmcnt(" VW ")" ::: "memory");                       \
    __builtin_amdgcn_s_barrier();                                               \
    __builtin_amdgcn_sched_barrier(0);                                          \
    if (DOSTAGE) stageAB((T) + 1, (PH));                                        \
    const int hb_ = (((T) & 1) * 2 + (PH)) * 16384;                             \
    short8 af[8], bf[4];                                                        \
    _Pragma("unroll")                                                           \
    for (int fi = 0; fi < 8; ++fi)                                              \
      af[fi] = *(const short8*)(lds + hb_ + a_rd + fi * 1024);                  \
    _Pragma("unroll")                                                           \
    for (int fj = 0; fj < 4; ++fj)                                              \
      bf[fj] = *(const short8*)(lds + 65536 + hb_ + b_rd + fj * 1024);          \
    __builtin_amdgcn_s_setprio(1);                                              \
    _Pragma("unroll")                                                           \
    for (int fi = 0; fi < 8; ++fi) {                                            \
      _Pragma("unroll")                                                         \
      for (int fj = 0; fj < 4; ++fj)                                            \
        acc[fi][fj] = __builtin_amdgcn_mfma_f32_16x16x32_bf16(af[fi], bf[fj],   \
                                                              acc[fi][fj], 0, 0, 0); \
    }                                                                           \
    __builtin_amdgcn_s_setprio(0);                                              \
  }

  stageAB(0, 0);
  stageAB(0, 1);
#pragma unroll 1
  for (int t = 0; t < nt - 1; ++t) {
    GPHASE(t, 0, "4", true);
    GPHASE(t, 1, "4", true);
  }
  GPHASE(nt - 1, 0, "4", false);
  GPHASE(nt - 1, 1, "0", false);
#undef GPHASE

  u16* Cp = Cpart + (size_t)z * ((size_t)M * N);
  const int rq = (lane >> 4) * 4;
  const int cq = lane & 15;
#pragma unroll
  for (int fi = 0; fi < 8; ++fi)
#pragma unroll
    for (int fj = 0; fj < 4; ++fj) {
      const int row = m0 + wr * 128 + fi * 16 + rq;
      const int col = n0 + wc * 64 + fj * 16 + cq;
#pragma unroll
      for (int q = 0; q < 4; ++q)
        Cp[(size_t)(row + q) * N + col] = f32_bf16(acc[fi][fj][q]);
    }
}

// ---------------- FC1 reduction: 8 bf16 partial slabs + bias + ReLU -> bf16 ---
__global__ __launch_bounds__(256) void reduce_bias8(
    const u16* __restrict__ P8, const float* __restrict__ bias,
    u16* __restrict__ out) {
  const int i4 = (blockIdx.x * 256 + threadIdx.x) * 4;
  if (i4 >= 2097152) return;
  const int nb = i4 & 1023;
  float s0 = bias[nb], s1 = bias[nb + 1], s2 = bias[nb + 2], s3 = bias[nb + 3];
#pragma unroll
  for (int j = 0; j < 8; ++j) {
    const us4 v = *(const us4*)(P8 + (size_t)j * 2097152 + i4);
    s0 += bf16_f32(v.x); s1 += bf16_f32(v.y); s2 += bf16_f32(v.z); s3 += bf16_f32(v.w);
  }
  us4 o;
  o.x = f32_bf16(fmaxf(s0, 0.f)); o.y = f32_bf16(fmaxf(s1, 0.f));
  o.z = f32_bf16(fmaxf(s2, 0.f)); o.w = f32_bf16(fmaxf(s3, 0.f));
  *(us4*)(out + i4) = o;
}

// ---------------- old split-K BT-GEMM (f32 partials) for FC2 / proj -----------
template<int BM, int BN, int WGM, int WGN>
__global__ __launch_bounds__(256)
void gemm_bt_splitk(const u16* __restrict__ A, int lda,
                    const u16* __restrict__ B, int ldb,
                    float* __restrict__ Cpart, int M, int N, int Ksplit) {
  constexpr int BK = 64;
  constexpr int WM = BM / WGM, WN = BN / WGN;
  constexpr int FM = WM / 16, FN = WN / 16;
  constexpr int AITER = BM * BK / 2048;
  constexpr int BITER = BN * BK / 2048;
  __shared__ u16 Asm_[BM * BK];
  __shared__ u16 Bsm_[BN * BK];
  const int tid = threadIdx.x;
  const int wave = tid >> 6, lane = tid & 63;
  const int wr = wave / WGN, wc = wave % WGN;
  const int m0 = blockIdx.x * BM, n0 = blockIdx.y * BN;
  const int kbase0 = blockIdx.z * Ksplit;

  f32x4 acc[FM][FN];
#pragma unroll
  for (int i = 0; i < FM; ++i)
#pragma unroll
    for (int j = 0; j < FN; ++j)
      acc[i][j] = f32x4{0.0f, 0.0f, 0.0f, 0.0f};

  const int ar = tid >> 3;
  const int acsub = (tid & 7) * 8;
  const int fr = lane & 15;
  const int kq = (lane >> 4) * 8;

  for (int kt = 0; kt < Ksplit; kt += BK) {
    const int kb = kbase0 + kt;
#pragma unroll
    for (int it = 0; it < AITER; ++it) {
      const u16* src = A + (size_t)(m0 + it * 32 + ar) * lda + kb + acsub;
      load_lds16(src, (char*)Asm_ + it * 4096 + wave * 1024);
    }
#pragma unroll
    for (int it = 0; it < BITER; ++it) {
      const u16* src = B + (size_t)(n0 + it * 32 + ar) * ldb + kb + acsub;
      load_lds16(src, (char*)Bsm_ + it * 4096 + wave * 1024);
    }
    __syncthreads();
#pragma unroll
    for (int kk = 0; kk < BK; kk += 32) {
      short8 af[FM], bfr[FN];
#pragma unroll
      for (int i = 0; i < FM; ++i)
        af[i] = *(const short8*)(Asm_ + (wr * WM + i * 16 + fr) * BK + kk + kq);
#pragma unroll
      for (int j = 0; j < FN; ++j)
        bfr[j] = *(const short8*)(Bsm_ + (wc * WN + j * 16 + fr) * BK + kk + kq);
#pragma unroll
      for (int i = 0; i < FM; ++i)
#pragma unroll
        for (int j = 0; j < FN; ++j)
          acc[i][j] = __builtin_amdgcn_mfma_f32_16x16x32_bf16(af[i], bfr[j], acc[i][j], 0, 0, 0);
    }
    __syncthreads();
  }

  float* Cp = Cpart + (size_t)blockIdx.z * ((size_t)M * N);
  const int rq = (lane >> 4) * 4;
  const int cq = lane & 15;
#pragma unroll
  for (int i = 0; i < FM; ++i)
#pragma unroll
    for (int j = 0; j < FN; ++j) {
      const int row = m0 + wr * WM + i * 16 + rq;
      const int col = n0 + wc * WN + j * 16 + cq;
      float* o = Cp + (size_t)row * N + col;
#pragma unroll
      for (int q = 0; q < 4; ++q)
        o[(size_t)q * N] = acc[i][j][q];
    }
}

template<int S, bool RELU>
__global__ __launch_bounds__(256) void reduce_bias_bf16(
    const float* __restrict__ P, const float* __restrict__ bias,
    u16* __restrict__ out, int MN, int Nmask) {
  const int i = blockIdx.x * 256 + threadIdx.x;
  if (i >= MN) return;
  float s = bias[i & Nmask];
#pragma unroll
  for (int j = 0; j < S; ++j) s += P[(size_t)j * MN + i];
  if (RELU) s = fmaxf(s, 0.0f);
  out[i] = f32_bf16(s);
}

__global__ __launch_bounds__(256) void reduce_out(
    const float* __restrict__ P, const float* __restrict__ bp,
    float* __restrict__ out) {
  const int i = blockIdx.x * 256 + threadIdx.x;
  if (i >= 2048 * 93) return;
  const int mrow = i / 93;
  const int n = i - mrow * 93;
  float s = bp[n];
#pragma unroll
  for (int j = 0; j < 8; ++j) s += P[(size_t)j * (2048 * 96) + mrow * 96 + n];
  out[i] = s;
}

// ---------------- launch ------------------------------------------------------
extern "C" void kernel_launch(void* const* d_in, const int* in_sizes, int n_in,
                              void* d_out, int out_size, void* d_ws, size_t ws_size,
                              hipStream_t stream) {
  const float* p3   = (const float*)d_in[0];
  const float* p4   = (const float*)d_in[1];
  const float* p5   = (const float*)d_in[2];
  const float* bbox = (const float*)d_in[3];
  const int*   anc  = (const int*)d_in[4];
  const float* W1   = (const float*)d_in[5];
  const float* b1   = (const float*)d_in[6];
  const float* W2   = (const float*)d_in[7];
  const float* b2   = (const float*)d_in[8];
  const float* Wp   = (const float*)d_in[9];
  const float* bp   = (const float*)d_in[10];
  float* out = (float*)d_out;

  char* ws = (char*)d_ws;
  // Permanent: X [0, 51380224), W1b [51380224, 77070336)
  u16* X   = (u16*)(ws);
  u16* W1b = (u16*)(ws + 51380224);
  // Shared region R at 77070336 (size 44236800; total 121307136 B, proven fit):
  //   Phase A (transpose+roi): t3|t4|t5 fp16 (44040192 B)
  //   Phase B (after roi): W2b|Wpb|H1|H2|{P8 bf16 33554432 / Pf f32 <=16777216}
  char* R = ws + 77070336;
  u16* t3  = (u16*)(R);
  u16* t4  = (u16*)(R + 33554432);
  u16* t5  = (u16*)(R + 41943040);
  u16* W2b = (u16*)(R);
  u16* Wpb = (u16*)(R + 2097152);
  u16* H1  = (u16*)(R + 2293760);
  u16* H2  = (u16*)(R + 6488064);
  u16*   P8 = (u16*)(R + 10682368);   // 8 x 2048x1024 bf16 (FC1 partials)
  float* Pf = (float*)(R + 10682368); // f32 partials for FC2/proj (reuse)
  (void)ws_size; (void)in_sizes; (void)n_in; (void)out_size;

  // Phase A: transpose feats to channels-last fp16, then ROI gather
  hipLaunchKernelGGL(transpose_feats, dim3(21504), dim3(256), 0, stream, p3, p4, p5, t3, t4, t5);
  hipLaunchKernelGGL(roi_pool3, dim3(2048), dim3(256), 0, stream, t3, t4, t5, bbox, anc, X);
  // Phase B: all weights -> bf16 in one launch (W2b/Wpb alias t3 -> after roi)
  hipLaunchKernelGGL(cvt_all, dim3(13664), dim3(256), 0, stream, W1, W2, Wp, W1b, W2b, Wpb);
  // FC1: X @ W1^T — 256² 2-phase pipeline (verified), uneven split-K=8 (25/24)
  hipLaunchKernelGGL(gemm8_bt, dim3(256), dim3(512), 0, stream,
                     X, 12544, W1b, 12544, P8, 2048, 1024, 8, 4);
  hipLaunchKernelGGL(reduce_bias8, dim3(2048), dim3(256), 0, stream, P8, b1, H1);
  // FC2: H1 @ W2^T, split-K=2 (old structure)
  hipLaunchKernelGGL((gemm_bt_splitk<128,128,2,2>), dim3(16, 8, 2), dim3(256), 0, stream,
                     H1, 1024, W2b, 1024, Pf, 2048, 1024, 512);
  hipLaunchKernelGGL((reduce_bias_bf16<2,true>), dim3(8192), dim3(256), 0, stream,
                     Pf, b2, H2, 2048 * 1024, 1023);
  // proj: H2 @ Wp^T (N padded to 96), split-K=8
  hipLaunchKernelGGL((gemm_bt_splitk<128,96,4,1>), dim3(16, 1, 8), dim3(256), 0, stream,
                     H2, 1024, Wpb, 1024, Pf, 2048, 96, 128);
  hipLaunchKernelGGL(reduce_out, dim3(744), dim3(256), 0, stream, Pf, bp, out);
}